// Round 12
// baseline (683.135 us; speedup 1.0000x reference)
//
#include <hip/hip_runtime.h>
#include <hip/hip_bf16.h>

#define NN   40000
#define NE   160000
#define ETOT 200000   // NE + NN self loops
#define FIN  602
#define NH1  8
#define C1   256
#define F1   2048     // NH1*C1
#define C2   42
#define NEG  0.2f
#define NB   157      // ceil(NN/256)
#define KP   608      // FIN padded to mult of 32
#define MP   40192    // NN padded to mult of 256 (157*256)
#define CSS  264      // Cs LDS row stride (u16), padded vs 256 to spread banks

typedef unsigned short u16;
typedef unsigned int   u32;
typedef __bf16 bf16x8 __attribute__((ext_vector_type(8)));
typedef float  f32x4  __attribute__((ext_vector_type(4)));

__device__ __forceinline__ float bfu(u16 v){ return __uint_as_float(((u32)v) << 16); }
__device__ __forceinline__ float bflo(u32 u){ return __uint_as_float(u << 16); }
__device__ __forceinline__ float bfhi(u32 u){ return __uint_as_float(u & 0xffff0000u); }
__device__ __forceinline__ u16 f2bf(float f){
  u32 u = __float_as_uint(f);
  u32 r = (u + 0x7fffu + ((u >> 16) & 1u)) >> 16;   // RNE
  return (u16)r;
}

// async global->LDS, 16B per lane; LDS dest = wave-uniform base + lane*16
__device__ __forceinline__ void gl_lds16(const u16* g, u16* l) {
  __builtin_amdgcn_global_load_lds(
      (const __attribute__((address_space(1))) u32*)(g),
      (__attribute__((address_space(3))) u32*)(l), 16, 0, 0);
}

// ================= dtype probe =================
__global__ void probe_k(const u32* __restrict__ xw, const int* __restrict__ ei,
                        int* __restrict__ flags) {
  if (threadIdx.x == 0) {
    int zc = 0;
    for (int k = 0; k < 64; ++k) zc += (ei[2*k + 1] == 0) ? 1 : 0;
    flags[0] = (zc == 64) ? 1 : 0;
    int inr = 0;
    for (int k = 0; k < 64; ++k) {
      u32 low = xw[k] & 0xffffu;
      int e = (int)((low >> 7) & 0xff);
      inr += (e >= 100 && e <= 140) ? 1 : 0;
    }
    flags[1] = (inr >= 32) ? 0 : 1;
  }
}

__global__ void cvt_f32_k(const void* __restrict__ src, float* __restrict__ dst, int n,
                          const int* __restrict__ flags) {
  int i = blockIdx.x * 256 + threadIdx.x;
  if (i >= n) return;
  dst[i] = flags[1] ? ((const float*)src)[i] : bfu(((const u16*)src)[i]);
}

// xb[MP][KP] = x as bf16, zero-padded rows/cols
__global__ void xb_k(const void* __restrict__ x, u16* __restrict__ xb,
                     const int* __restrict__ flags) {
  int k = blockIdx.x * 256 + threadIdx.x;
  int row = blockIdx.y;
  if (k >= KP) return;
  u16 v = 0;
  if (row < NN && k < FIN)
    v = flags[1] ? f2bf(((const float*)x)[(size_t)row * FIN + k])
                 : ((const u16*)x)[(size_t)row * FIN + k];
  xb[(size_t)row * KP + k] = v;
}

// W1t[n][k] = W1[k][n], k padded to 608 with zeros. bf16.
__global__ void w1t_k(const void* __restrict__ W1, u16* __restrict__ w1t,
                      const int* __restrict__ flags) {
  int n = blockIdx.x * 256 + threadIdx.x;
  int k = blockIdx.y;
  if (n >= F1) return;
  u16 v = 0;
  if (k < FIN) v = flags[1] ? f2bf(((const float*)W1)[(size_t)k * F1 + n])
                            : ((const u16*)W1)[(size_t)k * F1 + n];
  w1t[(size_t)n * KP + k] = v;
}

// w2t[c][k] = W2[k][c], c padded 42->64 with zeros. bf16.
__global__ void w2t_k(const void* __restrict__ W2, u16* __restrict__ w2t,
                      const int* __restrict__ flags) {
  int i = blockIdx.x * 256 + threadIdx.x;
  if (i >= 64 * F1) return;
  int c = i >> 11, k = i & (F1 - 1);
  u16 v = 0;
  if (c < C2) v = flags[1] ? f2bf(((const float*)W2)[(size_t)k * C2 + c])
                           : ((const u16*)W2)[(size_t)k * C2 + c];
  w2t[i] = v;
}

// ================= CSR build =================
__device__ __forceinline__ void edge_sd(const int* __restrict__ ei, int e, int imode,
                                        int& s, int& d) {
  if (e < NE) {
    if (imode) { s = ei[2*e]; d = ei[2*(NE + e)]; }
    else       { s = ei[e];   d = ei[NE + e];     }
  } else { s = d = e - NE; }
}

__global__ void deg_k(const int* __restrict__ ei, int* __restrict__ deg,
                      const int* __restrict__ flags) {
  int e = blockIdx.x * 256 + threadIdx.x;
  if (e >= ETOT) return;
  int s, d; edge_sd(ei, e, flags[0], s, d);
  atomicAdd(&deg[d], 1);
}

__global__ __launch_bounds__(256) void scan1_k(const int* __restrict__ deg,
                                               int* __restrict__ tmp, int* __restrict__ bsum) {
  __shared__ int s[256];
  int b = blockIdx.x, t = threadIdx.x, i = b * 256 + t;
  int v = (i < NN) ? deg[i] : 0;
  s[t] = v; __syncthreads();
  for (int o = 1; o < 256; o <<= 1) {
    int u = (t >= o) ? s[t - o] : 0;
    __syncthreads(); s[t] += u; __syncthreads();
  }
  if (i < NN) tmp[i] = s[t];
  if (t == 255) bsum[b] = s[255];
}

__global__ __launch_bounds__(256) void scan2_k(int* __restrict__ bsum) {
  __shared__ int s[256];
  int t = threadIdx.x;
  int v = (t < NB) ? bsum[t] : 0;
  s[t] = v; __syncthreads();
  for (int o = 1; o < 256; o <<= 1) {
    int u = (t >= o) ? s[t - o] : 0;
    __syncthreads(); s[t] += u; __syncthreads();
  }
  if (t < NB) bsum[t] = s[t];
}

__global__ void scan3_k(const int* __restrict__ deg, const int* __restrict__ tmp,
                        const int* __restrict__ bsum, int* __restrict__ start, int* __restrict__ cur) {
  int i = blockIdx.x * 256 + threadIdx.x;
  if (i >= NN) return;
  int b = i >> 8;
  int off = b ? bsum[b - 1] : 0;
  int excl = tmp[i] - deg[i] + off;
  start[i] = excl; cur[i] = excl;
}

__global__ void fill_k(const int* __restrict__ ei, int* __restrict__ cur,
                       int* __restrict__ csr_src, int* __restrict__ csr_dst,
                       const int* __restrict__ flags) {
  int e = blockIdx.x * 256 + threadIdx.x;
  if (e >= ETOT) return;
  int s, d; edge_sd(ei, e, flags[0], s, d);
  int pos = atomicAdd(&cur[d], 1);
  csr_src[pos] = s; csr_dst[pos] = d;
}

// ================= GEMM1 path A: 256x256 tile, BK=32, 8 waves (2x4),
// double-buffered global_load_lds with COUNTED vmcnt (T4): prefetch loads stay
// in flight across the barrier instead of being drained by __syncthreads.
__global__ __launch_bounds__(512) void gemm1c_k(const u16* __restrict__ xb,
                                                const u16* __restrict__ w1t,
                                                u16* __restrict__ h1,
                                                const float* __restrict__ as1c,
                                                const float* __restrict__ ad1c,
                                                float* __restrict__ a_s1,
                                                float* __restrict__ a_d1) {
  __shared__ u16 As[2 * 8192];   // [buf][256 rows][32 k] = 32 KB (reused as Cs in epilogue)
  __shared__ u16 Bs[2 * 8192];
  const int t = threadIdx.x;
  const int lane = t & 63, wid = t >> 6;   // 8 waves
  const int wr = wid >> 2, wc = wid & 3;   // 2 x 4 wave grid, wave tile 128x64
  const int m0 = blockIdx.y * 256, n0 = blockIdx.x * 256;
  const int l16 = lane & 15;
  f32x4 acc[8][4];
  #pragma unroll
  for (int i = 0; i < 8; ++i)
    #pragma unroll
    for (int j = 0; j < 4; ++j) acc[i][j] = (f32x4){0.f, 0.f, 0.f, 0.f};

  const int kc = ((t & 3) ^ ((t >> 3) & 3)) * 8;
  const size_t sa0 = (size_t)(m0 + (t >> 2)) * KP + kc;
  const size_t sa1 = sa0 + (size_t)128 * KP;
  const size_t sb0 = (size_t)(n0 + (t >> 2)) * KP + kc;
  const size_t sb1 = sb0 + (size_t)128 * KP;

  const int fsw = ((lane >> 4) ^ ((l16 >> 1) & 3)) << 3;
  const int rdA = (wr * 128 + l16) * 32 + fsw;   // + mi*512
  const int rdB = (wc * 64 + l16) * 32 + fsw;    // + ni*512

#define STAGE(K0, B) do {                                  \
    u16* a_ = As + (B) * 8192 + (wid << 9);                \
    u16* b_ = Bs + (B) * 8192 + (wid << 9);                \
    gl_lds16(xb  + sa0 + (K0), a_);                        \
    gl_lds16(xb  + sa1 + (K0), a_ + 4096);                 \
    gl_lds16(w1t + sb0 + (K0), b_);                        \
    gl_lds16(w1t + sb1 + (K0), b_ + 4096);                 \
  } while (0)

  STAGE(0, 0);
  int cur = 0;
  for (int k0 = 0; k0 < KP; k0 += 32) {
    if (k0 + 32 < KP) {
      STAGE(k0 + 32, cur ^ 1);                       // 4 new loads in flight
      asm volatile("s_waitcnt vmcnt(4)" ::: "memory");  // oldest 4 (cur tile) landed
    } else {
      asm volatile("s_waitcnt vmcnt(0)" ::: "memory");  // final tile: full drain
    }
    __builtin_amdgcn_s_barrier();       // all waves' cur loads landed
    __builtin_amdgcn_sched_barrier(0);  // pin ds_reads after the barrier
    const u16* Ab = As + cur * 8192;
    const u16* Bb = Bs + cur * 8192;
    bf16x8 bfr[4];
    #pragma unroll
    for (int ni = 0; ni < 4; ++ni)
      bfr[ni] = *(const bf16x8*)&Bb[rdB + ni * 512];
    #pragma unroll
    for (int mi = 0; mi < 8; ++mi) {
      bf16x8 af = *(const bf16x8*)&Ab[rdA + mi * 512];
      #pragma unroll
      for (int ni = 0; ni < 4; ++ni)
        acc[mi][ni] = __builtin_amdgcn_mfma_f32_16x16x32_bf16(af, bfr[ni], acc[mi][ni], 0, 0, 0);
    }
    __builtin_amdgcn_sched_barrier(0);  // keep reads of cur above barrier 2
    __builtin_amdgcn_s_barrier();       // all reads of cur done -> next iter may overwrite
    cur ^= 1;
  }
#undef STAGE

  // ---- fused att1: per-row weighted col sums -> shfl reduce -> atomic partials
  const int h0 = n0 >> 8;          // head of this col tile (N-tile == C1)
  const int lr4 = (lane >> 4) * 4;
  #pragma unroll
  for (int mi = 0; mi < 8; ++mi) {
    float ps[4] = {0.f, 0.f, 0.f, 0.f}, pd[4] = {0.f, 0.f, 0.f, 0.f};
    #pragma unroll
    for (int ni = 0; ni < 4; ++ni) {
      int col = n0 + wc * 64 + ni * 16 + l16;
      float wsv = as1c[col], wdv = ad1c[col];
      #pragma unroll
      for (int r = 0; r < 4; ++r) {
        float v = acc[mi][ni][r];
        ps[r] += v * wsv;
        pd[r] += v * wdv;
      }
    }
    #pragma unroll
    for (int o = 1; o < 16; o <<= 1) {
      #pragma unroll
      for (int r = 0; r < 4; ++r) {
        ps[r] += __shfl_xor(ps[r], o, 64);
        pd[r] += __shfl_xor(pd[r], o, 64);
      }
    }
    if (l16 == 0) {
      int rowb = m0 + wr * 128 + mi * 16 + lr4;
      #pragma unroll
      for (int r = 0; r < 4; ++r) {
        int row = rowb + r;
        if (row < NN) {
          atomicAdd(&a_s1[row * NH1 + h0], ps[r]);
          atomicAdd(&a_d1[row * NH1 + h0], pd[r]);
        }
      }
    }
  }

  // ---- C store via LDS (coalesced): 8 passes of 32 rows; Cs reuses As (16.9 KB)
  u16* Cs = As;
  const int rrow = t >> 4;          // 0..31 LDS row
  const int rchk = t & 15;          // 16-u16 (32B) chunk within row
  for (int mi = 0; mi < 8; ++mi) {
    __syncthreads();               // previous pass readback done
    #pragma unroll
    for (int ni = 0; ni < 4; ++ni)
      #pragma unroll
      for (int r = 0; r < 4; ++r)
        Cs[(wr * 16 + lr4 + r) * CSS + wc * 64 + ni * 16 + l16] = f2bf(acc[mi][ni][r]);
    __syncthreads();
    int grow = m0 + (rrow >> 4) * 128 + mi * 16 + (rrow & 15);
    if (grow < NN) {
      const uint4* src = (const uint4*)&Cs[rrow * CSS + rchk * 16];
      uint4 v0 = src[0], v1 = src[1];
      uint4* dst = (uint4*)&h1[(size_t)grow * F1 + n0 + rchk * 16];
      dst[0] = v0; dst[1] = v1;
    }
  }
}

// ================= GEMM1 path B (fallback, reg-staged, dual-dtype) =================
__global__ __launch_bounds__(256) void gemm1m_k(const void* __restrict__ xv,
                                                const u16* __restrict__ w1t,
                                                u16* __restrict__ h1,
                                                const int* __restrict__ flags) {
  __shared__ u16 As[128][40];
  __shared__ u16 Bs[128][40];
  const int fm = flags[1];
  const int t = threadIdx.x;
  const int lane = t & 63, wid = t >> 6;
  const int wr = wid >> 1, wc = wid & 1;
  const int m0 = blockIdx.y * 128, n0 = blockIdx.x * 128;
  const int l16 = lane & 15, lk = (lane >> 4) * 8;
  f32x4 acc[4][4];
  #pragma unroll
  for (int i = 0; i < 4; ++i)
    #pragma unroll
    for (int j = 0; j < 4; ++j) acc[i][j] = (f32x4){0.f, 0.f, 0.f, 0.f};
  const int arow = t >> 2;
  const int akb  = (t & 3) * 8;
  for (int k0 = 0; k0 < KP; k0 += 32) {
    #pragma unroll
    for (int i = 0; i < 2; ++i) {
      int row = arow + i * 64;
      int rg = m0 + row;
      u32 d0 = 0, d1 = 0, d2 = 0, d3 = 0;
      if (rg < NN) {
        if (k0 + 32 <= FIN) {
          if (fm) {
            const float* xp = (const float*)xv + (size_t)rg * FIN + k0 + akb;
            float2 p0 = *(const float2*)(xp);
            float2 p1 = *(const float2*)(xp + 2);
            float2 p2 = *(const float2*)(xp + 4);
            float2 p3 = *(const float2*)(xp + 6);
            d0 = (u32)f2bf(p0.x) | ((u32)f2bf(p0.y) << 16);
            d1 = (u32)f2bf(p1.x) | ((u32)f2bf(p1.y) << 16);
            d2 = (u32)f2bf(p2.x) | ((u32)f2bf(p2.y) << 16);
            d3 = (u32)f2bf(p3.x) | ((u32)f2bf(p3.y) << 16);
          } else {
            const u16* xp = (const u16*)xv + (size_t)rg * FIN + k0 + akb;
            d0 = *(const u32*)(xp);
            d1 = *(const u32*)(xp + 2);
            d2 = *(const u32*)(xp + 4);
            d3 = *(const u32*)(xp + 6);
          }
        } else {
          u16 e[8];
          #pragma unroll
          for (int q = 0; q < 8; ++q) {
            int k = k0 + akb + q;
            e[q] = 0;
            if (k < FIN)
              e[q] = fm ? f2bf(((const float*)xv)[(size_t)rg * FIN + k])
                        : ((const u16*)xv)[(size_t)rg * FIN + k];
          }
          d0 = (u32)e[0] | ((u32)e[1] << 16);
          d1 = (u32)e[2] | ((u32)e[3] << 16);
          d2 = (u32)e[4] | ((u32)e[5] << 16);
          d3 = (u32)e[6] | ((u32)e[7] << 16);
        }
      }
      *(uint4*)&As[row][akb] = make_uint4(d0, d1, d2, d3);
      const u16* wp = w1t + (size_t)(n0 + row) * KP + k0 + akb;
      *(uint4*)&Bs[row][akb] = *(const uint4*)wp;
    }
    __syncthreads();
    bf16x8 bfr[4];
    #pragma unroll
    for (int ni = 0; ni < 4; ++ni)
      bfr[ni] = *(const bf16x8*)&Bs[wc * 64 + ni * 16 + l16][lk];
    #pragma unroll
    for (int mi = 0; mi < 4; ++mi) {
      bf16x8 af = *(const bf16x8*)&As[wr * 64 + mi * 16 + l16][lk];
      #pragma unroll
      for (int ni = 0; ni < 4; ++ni)
        acc[mi][ni] = __builtin_amdgcn_mfma_f32_16x16x32_bf16(af, bfr[ni], acc[mi][ni], 0, 0, 0);
    }
    __syncthreads();
  }
  const int lr4 = (lane >> 4) * 4;
  #pragma unroll
  for (int mi = 0; mi < 4; ++mi) {
    #pragma unroll
    for (int r = 0; r < 4; ++r) {
      int row = m0 + wr * 64 + mi * 16 + lr4 + r;
      if (row < NN) {
        #pragma unroll
        for (int ni = 0; ni < 4; ++ni) {
          int col = n0 + wc * 64 + ni * 16 + l16;
          h1[(size_t)row * F1 + col] = f2bf(acc[mi][ni][r]);
        }
      }
    }
  }
}

// ================= attention scalars (fallback path only)
__global__ __launch_bounds__(256) void att1_k(const u16* __restrict__ h1,
                                              const float* __restrict__ as1c, const float* __restrict__ ad1c,
                                              float* __restrict__ a_s, float* __restrict__ a_d) {
  int n = blockIdx.x, t = threadIdx.x;
  int h = t >> 5, l = t & 31;
  int base = h * C1 + l * 8;
  const u16* hp = h1 + (size_t)n * F1 + base;
  uint4 v = *(const uint4*)hp;
  u32 w[4] = {v.x, v.y, v.z, v.w};
  float ss = 0.f, sd = 0.f;
  #pragma unroll
  for (int p = 0; p < 4; ++p) {
    float e0 = bflo(w[p]), e1 = bfhi(w[p]);
    ss += e0 * as1c[base + 2*p] + e1 * as1c[base + 2*p + 1];
    sd += e0 * ad1c[base + 2*p] + e1 * ad1c[base + 2*p + 1];
  }
  #pragma unroll
  for (int o = 16; o > 0; o >>= 1) {
    ss += __shfl_down(ss, o, 32);
    sd += __shfl_down(sd, o, 32);
  }
  if (l == 0) { a_s[n * NH1 + h] = ss; a_d[n * NH1 + h] = sd; }
}

// ================= fused: gather(vectorized)+bias+ReLU -> LDS -> MFMA @ w2t -> h2
// 256 threads (round-5/6 proven); thread t owns 8 channels, head t>>5; scores inline
__global__ __launch_bounds__(256) void gfuse_k(const int* __restrict__ start, const int* __restrict__ deg,
                                               const int* __restrict__ csr_src,
                                               const float* __restrict__ a_s1, const float* __restrict__ a_d1,
                                               const u16* __restrict__ h1, const float* __restrict__ b1c,
                                               const u16* __restrict__ w2t, float* __restrict__ h2) {
  __shared__ u16 rowsL[16 * F1];   // 64 KB
  int t = threadIdx.x;
  int nb = blockIdx.x * 16;
  int h = t >> 5;
  int c0 = t * 8;
  float4 bA = *(const float4*)(b1c + c0);
  float4 bB = *(const float4*)(b1c + c0 + 4);
  for (int i = 0; i < 16; ++i) {
    int n = nb + i;
    int s0 = start[n], jend = s0 + deg[n];
    float ad = a_d1[n * NH1 + h];
    float a0=0.f,a1=0.f,a2=0.f,a3=0.f,a4=0.f,a5=0.f,a6=0.f,a7=0.f,den=0.f;
    int j = s0;
    for (; j + 2 <= jend; j += 2) {
      int sA = csr_src[j], sB = csr_src[j + 1];
      float vA = a_s1[sA * NH1 + h] + ad;
      float vB = a_s1[sB * NH1 + h] + ad;
      vA = vA > 0.f ? vA : NEG * vA;
      vB = vB > 0.f ? vB : NEG * vB;
      float eA = expf(vA), eB = expf(vB);
      uint4 uA = *(const uint4*)(h1 + (size_t)sA * F1 + c0);
      uint4 uB = *(const uint4*)(h1 + (size_t)sB * F1 + c0);
      den += eA + eB;
      a0 += eA * bflo(uA.x) + eB * bflo(uB.x);
      a1 += eA * bfhi(uA.x) + eB * bfhi(uB.x);
      a2 += eA * bflo(uA.y) + eB * bflo(uB.y);
      a3 += eA * bfhi(uA.y) + eB * bfhi(uB.y);
      a4 += eA * bflo(uA.z) + eB * bflo(uB.z);
      a5 += eA * bfhi(uA.z) + eB * bfhi(uB.z);
      a6 += eA * bflo(uA.w) + eB * bflo(uB.w);
      a7 += eA * bfhi(uA.w) + eB * bfhi(uB.w);
    }
    if (j < jend) {
      int sA = csr_src[j];
      float vA = a_s1[sA * NH1 + h] + ad;
      vA = vA > 0.f ? vA : NEG * vA;
      float eA = expf(vA);
      uint4 uA = *(const uint4*)(h1 + (size_t)sA * F1 + c0);
      den += eA;
      a0 += eA * bflo(uA.x); a1 += eA * bfhi(uA.x);
      a2 += eA * bflo(uA.y); a3 += eA * bfhi(uA.y);
      a4 += eA * bflo(uA.z); a5 += eA * bfhi(uA.z);
      a6 += eA * bflo(uA.w); a7 += eA * bfhi(uA.w);
    }
    float inv = 1.f / (den + 1e-16f);
    u16 o0 = f2bf(fmaxf(a0 * inv + bA.x, 0.f));
    u16 o1 = f2bf(fmaxf(a1 * inv + bA.y, 0.f));
    u16 o2 = f2bf(fmaxf(a2 * inv + bA.z, 0.f));
    u16 o3 = f2bf(fmaxf(a3 * inv + bA.w, 0.f));
    u16 o4 = f2bf(fmaxf(a4 * inv + bB.x, 0.f));
    u16 o5 = f2bf(fmaxf(a5 * inv + bB.y, 0.f));
    u16 o6 = f2bf(fmaxf(a6 * inv + bB.z, 0.f));
    u16 o7 = f2bf(fmaxf(a7 * inv + bB.w, 0.f));
    uint4 pk;
    pk.x = (u32)o0 | ((u32)o1 << 16);
    pk.y = (u32)o2 | ((u32)o3 << 16);
    pk.z = (u32)o4 | ((u32)o5 << 16);
    pk.w = (u32)o6 | ((u32)o7 << 16);
    int sw = (i & 7) << 3;
    *(uint4*)&rowsL[i * F1 + (c0 ^ sw)] = pk;
  }
  __syncthreads();
  // phase B: C[16 nodes][64 cols] = rowsL @ w2t^T
  int lane = t & 63, wid = t >> 6;
  int l16 = lane & 15, lk = (lane >> 4) * 8;
  const u16* wt = w2t + (size_t)(wid * 16 + l16) * F1;
  int sw = (l16 & 7) << 3;
  f32x4 acc2 = (f32x4){0.f, 0.f, 0.f, 0.f};
  for (int k0 = 0; k0 < F1; k0 += 32) {
    int kk = k0 + lk;
    bf16x8 af = *(const bf16x8*)&rowsL[l16 * F1 + (kk ^ sw)];
    bf16x8 bf = *(const bf16x8*)(wt + kk);
    acc2 = __builtin_amdgcn_mfma_f32_16x16x32_bf16(af, bf, acc2, 0, 0, 0);
  }
  int col = wid * 16 + l16;
  if (col < C2) {
    int mb = (lane >> 4) * 4;
    #pragma unroll
    for (int r = 0; r < 4; ++r)
      h2[(size_t)(nb + mb + r) * C2 + col] = acc2[r];
  }
}

// ================= attention scalars layer 2
__global__ __launch_bounds__(64) void att2_k(const float* __restrict__ h2,
                                             const float* __restrict__ as2, const float* __restrict__ ad2,
                                             float* __restrict__ a_s, float* __restrict__ a_d) {
  int n = blockIdx.x, t = threadIdx.x;
  float ss = 0.f, sd = 0.f;
  if (t < C2) {
    float v = h2[(size_t)n * C2 + t];
    ss = v * as2[t];
    sd = v * ad2[t];
  }
  #pragma unroll
  for (int o = 32; o > 0; o >>= 1) {
    ss += __shfl_down(ss, o, 64);
    sd += __shfl_down(sd, o, 64);
  }
  if (t == 0) { a_s[n] = ss; a_d[n] = sd; }
}

// ================= layer-2 gather + bias + log_softmax, dual-format output
__global__ __launch_bounds__(64) void gath2_k(const int* __restrict__ start, const int* __restrict__ deg,
                                              const int* __restrict__ csr_src,
                                              const float* __restrict__ a_s, const float* __restrict__ a_d,
                                              const float* __restrict__ h2, const float* __restrict__ b2,
                                              void* __restrict__ outv, const int* __restrict__ flags) {
  int n = blockIdx.x, t = threadIdx.x;
  int s0 = start[n], cnt = deg[n];
  float ad = a_d[n];
  float acc = 0.f, den = 0.f;
  for (int j = s0; j < s0 + cnt; ++j) {
    int s = csr_src[j];
    float v = a_s[s] + ad;
    v = v > 0.f ? v : NEG * v;
    float e = expf(v);
    den += e;
    if (t < C2) acc += e * h2[(size_t)s * C2 + t];
  }
  float raw = (t < C2) ? acc / (den + 1e-16f) + b2[t] : -1e30f;
  float m = raw;
  #pragma unroll
  for (int o = 32; o > 0; o >>= 1) m = fmaxf(m, __shfl_down(m, o, 64));
  m = __shfl(m, 0, 64);
  float e2 = (t < C2) ? expf(raw - m) : 0.f;
  float ssum = e2;
  #pragma unroll
  for (int o = 32; o > 0; o >>= 1) ssum += __shfl_down(ssum, o, 64);
  ssum = __shfl(ssum, 0, 64);
  if (t < C2) {
    float v = raw - m - logf(ssum);
    if (flags[1]) ((float*)outv)[(size_t)n * C2 + t] = v;
    else          ((u16*) outv)[(size_t)n * C2 + t] = f2bf(v);
  }
}

extern "C" void kernel_launch(void* const* d_in, const int* in_sizes, int n_in,
                              void* d_out, int out_size, void* d_ws, size_t ws_size,
                              hipStream_t stream) {
  const void* x   = d_in[0];
  const int*  ei  = (const int*)d_in[1];
  const void* W1  = d_in[2];
  const void* as1 = d_in[3];
  const void* ad1 = d_in[4];
  const void* b1  = d_in[5];
  const void* W2  = d_in[6];
  const void* as2 = d_in[7];
  const void* ad2 = d_in[8];
  const void* b2  = d_in[9];

  char* ws = (char*)d_ws;
  u16*   h1      = (u16*)  (ws);                  // 163,840,000
  float* h2      = (float*)(ws + 163840000);      //   6,720,000
  float* a_s1    = (float*)(ws + 170560000);      //   1,280,000
  float* a_d1    = (float*)(ws + 171840000);      //   1,280,000
  float* a_s2    = (float*)(ws + 173120000);      //     160,000
  float* a_d2    = (float*)(ws + 173280000);      //     160,000
  int*   deg     = (int*)  (ws + 173440000);      //     160,000
  int*   start   = (int*)  (ws + 173600000);      //     160,000
  int*   cur     = (int*)  (ws + 173760000);      //     160,000
  int*   tmp     = (int*)  (ws + 173920000);      //     160,000
  int*   csr_src = (int*)  (ws + 174080000);      //     800,000
  int*   csr_dst = (int*)  (ws + 174880000);      //     800,000
  int*   bsum    = (int*)  (ws + 175680000);      //       1,024
  u16*   w1t     = (u16*)  (ws + 175681024);      //   2,490,368
  u16*   w2t     = (u16*)  (ws + 178171392);      //     262,144
  float* as1c    = (float*)(ws + 178433536);      //       8,192
  float* ad1c    = (float*)(ws + 178441728);      //       8,192
  float* b1c     = (float*)(ws + 178449920);      //       8,192
  float* as2c    = (float*)(ws + 178458112);      //         256
  float* ad2c    = (float*)(ws + 178458368);      //         256
  float* b2c     = (float*)(ws + 178458624);      //         256
  int*   flags   = (int*)  (ws + 178458880);      //         256
  const size_t TOTAL_BASE = 178459136;
  u16*   xb      = (u16*)  (ws + TOTAL_BASE);     //  48,873,472 (path A only)
  const size_t TOTAL_A = TOTAL_BASE + (size_t)MP * KP * 2;  // 227,332,608 (< proven 233.6MB)
  if (ws_size < TOTAL_BASE) return;
  const bool pathA = (ws_size >= TOTAL_A);

  probe_k<<<1, 64, 0, stream>>>((const u32*)x, ei, flags);

  cvt_f32_k<<<(F1 + 255) / 256, 256, 0, stream>>>(as1, as1c, F1, flags);
  cvt_f32_k<<<(F1 + 255) / 256, 256, 0, stream>>>(ad1, ad1c, F1, flags);
  cvt_f32_k<<<(F1 + 255) / 256, 256, 0, stream>>>(b1, b1c, F1, flags);
  cvt_f32_k<<<1, 256, 0, stream>>>(as2, as2c, C2, flags);
  cvt_f32_k<<<1, 256, 0, stream>>>(ad2, ad2c, C2, flags);
  cvt_f32_k<<<1, 256, 0, stream>>>(b2, b2c, C2, flags);
  w1t_k<<<dim3(8, KP), 256, 0, stream>>>(W1, w1t, flags);
  w2t_k<<<(64 * F1 + 255) / 256, 256, 0, stream>>>(W2, w2t, flags);

  hipMemsetAsync(deg, 0, NN * sizeof(int), stream);
  hipMemsetAsync(a_s1, 0, 2 * NN * NH1 * sizeof(float), stream);  // a_s1 + a_d1 contiguous
  const int EB = (ETOT + 255) / 256;
  deg_k  <<<EB, 256, 0, stream>>>(ei, deg, flags);
  scan1_k<<<NB, 256, 0, stream>>>(deg, tmp, bsum);
  scan2_k<<<1, 256, 0, stream>>>(bsum);
  scan3_k<<<NB, 256, 0, stream>>>(deg, tmp, bsum, start, cur);
  fill_k <<<EB, 256, 0, stream>>>(ei, cur, csr_src, csr_dst, flags);

  if (pathA) {
    xb_k<<<dim3((KP + 255) / 256, MP), 256, 0, stream>>>(x, xb, flags);
    gemm1c_k<<<dim3(8, MP / 256), 512, 0, stream>>>(xb, w1t, h1, as1c, ad1c, a_s1, a_d1);
  } else {
    gemm1m_k<<<dim3(16, 313), 256, 0, stream>>>(x, w1t, h1, flags);
    att1_k<<<NN, 256, 0, stream>>>(h1, as1c, ad1c, a_s1, a_d1);
  }
  gfuse_k<<<NN / 16, 256, 0, stream>>>(start, deg, csr_src, a_s1, a_d1, h1, b1c, w2t, h2);

  att2_k<<<NN, 64, 0, stream>>>(h2, as2c, ad2c, a_s2, a_d2);
  gath2_k<<<NN, 64, 0, stream>>>(start, deg, csr_src, a_s2, a_d2, h2, b2c, d_out, flags);
}

// Round 13
// 623.069 us; speedup vs baseline: 1.0964x; 1.0964x over previous
//
#include <hip/hip_runtime.h>
#include <hip/hip_bf16.h>

#define NN   40000
#define NE   160000
#define ETOT 200000   // NE + NN self loops
#define FIN  602
#define NH1  8
#define C1   256
#define F1   2048     // NH1*C1
#define C2   42
#define NEG  0.2f
#define NB   157      // ceil(NN/256)
#define KP   608      // FIN padded to mult of 32
#define MP   40192    // NN padded to mult of 256 (157*256)
#define CSS  264      // Cs LDS row stride (u16), padded vs 256 to spread banks

typedef unsigned short u16;
typedef unsigned int   u32;
typedef __bf16 bf16x8 __attribute__((ext_vector_type(8)));
typedef float  f32x4  __attribute__((ext_vector_type(4)));

__device__ __forceinline__ float bfu(u16 v){ return __uint_as_float(((u32)v) << 16); }
__device__ __forceinline__ float bflo(u32 u){ return __uint_as_float(u << 16); }
__device__ __forceinline__ float bfhi(u32 u){ return __uint_as_float(u & 0xffff0000u); }
__device__ __forceinline__ u16 f2bf(float f){
  u32 u = __float_as_uint(f);
  u32 r = (u + 0x7fffu + ((u >> 16) & 1u)) >> 16;   // RNE
  return (u16)r;
}

// async global->LDS, 16B per lane; LDS dest = wave-uniform base + lane*16
__device__ __forceinline__ void gl_lds16(const u16* g, u16* l) {
  __builtin_amdgcn_global_load_lds(
      (const __attribute__((address_space(1))) u32*)(g),
      (__attribute__((address_space(3))) u32*)(l), 16, 0, 0);
}

// ================= dtype probe =================
__global__ void probe_k(const u32* __restrict__ xw, const int* __restrict__ ei,
                        int* __restrict__ flags) {
  if (threadIdx.x == 0) {
    int zc = 0;
    for (int k = 0; k < 64; ++k) zc += (ei[2*k + 1] == 0) ? 1 : 0;
    flags[0] = (zc == 64) ? 1 : 0;
    int inr = 0;
    for (int k = 0; k < 64; ++k) {
      u32 low = xw[k] & 0xffffu;
      int e = (int)((low >> 7) & 0xff);
      inr += (e >= 100 && e <= 140) ? 1 : 0;
    }
    flags[1] = (inr >= 32) ? 0 : 1;
  }
}

// all small f32 canonicalizations in one launch
__global__ void cvt_all_k(const void* __restrict__ as1, const void* __restrict__ ad1,
                          const void* __restrict__ b1,  const void* __restrict__ as2,
                          const void* __restrict__ ad2, const void* __restrict__ b2,
                          float* __restrict__ as1c, float* __restrict__ ad1c,
                          float* __restrict__ b1c,  float* __restrict__ as2c,
                          float* __restrict__ ad2c, float* __restrict__ b2c,
                          const int* __restrict__ flags) {
  int i = blockIdx.x * 256 + threadIdx.x;
  int fm = flags[1];
  if (i < F1) {
    as1c[i] = fm ? ((const float*)as1)[i] : bfu(((const u16*)as1)[i]);
    ad1c[i] = fm ? ((const float*)ad1)[i] : bfu(((const u16*)ad1)[i]);
    b1c[i]  = fm ? ((const float*)b1)[i]  : bfu(((const u16*)b1)[i]);
  }
  if (i < C2) {
    as2c[i] = fm ? ((const float*)as2)[i] : bfu(((const u16*)as2)[i]);
    ad2c[i] = fm ? ((const float*)ad2)[i] : bfu(((const u16*)ad2)[i]);
    b2c[i]  = fm ? ((const float*)b2)[i]  : bfu(((const u16*)b2)[i]);
  }
}

// xb[MP][KP] = x as bf16, zero-padded rows/cols
__global__ void xb_k(const void* __restrict__ x, u16* __restrict__ xb,
                     const int* __restrict__ flags) {
  int k = blockIdx.x * 256 + threadIdx.x;
  int row = blockIdx.y;
  if (k >= KP) return;
  u16 v = 0;
  if (row < NN && k < FIN)
    v = flags[1] ? f2bf(((const float*)x)[(size_t)row * FIN + k])
                 : ((const u16*)x)[(size_t)row * FIN + k];
  xb[(size_t)row * KP + k] = v;
}

// W1t[n][k] = W1[k][n], k padded to 608 with zeros. bf16.
__global__ void w1t_k(const void* __restrict__ W1, u16* __restrict__ w1t,
                      const int* __restrict__ flags) {
  int n = blockIdx.x * 256 + threadIdx.x;
  int k = blockIdx.y;
  if (n >= F1) return;
  u16 v = 0;
  if (k < FIN) v = flags[1] ? f2bf(((const float*)W1)[(size_t)k * F1 + n])
                            : ((const u16*)W1)[(size_t)k * F1 + n];
  w1t[(size_t)n * KP + k] = v;
}

// w2t[c][k] = W2[k][c], c padded 42->64 with zeros. bf16.
__global__ void w2t_k(const void* __restrict__ W2, u16* __restrict__ w2t,
                      const int* __restrict__ flags) {
  int i = blockIdx.x * 256 + threadIdx.x;
  if (i >= 64 * F1) return;
  int c = i >> 11, k = i & (F1 - 1);
  u16 v = 0;
  if (c < C2) v = flags[1] ? f2bf(((const float*)W2)[(size_t)k * C2 + c])
                           : ((const u16*)W2)[(size_t)k * C2 + c];
  w2t[i] = v;
}

// ================= CSR build =================
__device__ __forceinline__ void edge_sd(const int* __restrict__ ei, int e, int imode,
                                        int& s, int& d) {
  if (e < NE) {
    if (imode) { s = ei[2*e]; d = ei[2*(NE + e)]; }
    else       { s = ei[e];   d = ei[NE + e];     }
  } else { s = d = e - NE; }
}

__global__ void deg_k(const int* __restrict__ ei, int* __restrict__ deg,
                      const int* __restrict__ flags) {
  int e = blockIdx.x * 256 + threadIdx.x;
  if (e >= ETOT) return;
  int s, d; edge_sd(ei, e, flags[0], s, d);
  atomicAdd(&deg[d], 1);
}

__global__ __launch_bounds__(256) void scan1_k(const int* __restrict__ deg,
                                               int* __restrict__ tmp, int* __restrict__ bsum) {
  __shared__ int s[256];
  int b = blockIdx.x, t = threadIdx.x, i = b * 256 + t;
  int v = (i < NN) ? deg[i] : 0;
  s[t] = v; __syncthreads();
  for (int o = 1; o < 256; o <<= 1) {
    int u = (t >= o) ? s[t - o] : 0;
    __syncthreads(); s[t] += u; __syncthreads();
  }
  if (i < NN) tmp[i] = s[t];
  if (t == 255) bsum[b] = s[255];
}

__global__ __launch_bounds__(256) void scan2_k(int* __restrict__ bsum) {
  __shared__ int s[256];
  int t = threadIdx.x;
  int v = (t < NB) ? bsum[t] : 0;
  s[t] = v; __syncthreads();
  for (int o = 1; o < 256; o <<= 1) {
    int u = (t >= o) ? s[t - o] : 0;
    __syncthreads(); s[t] += u; __syncthreads();
  }
  if (t < NB) bsum[t] = s[t];
}

__global__ void scan3_k(const int* __restrict__ deg, const int* __restrict__ tmp,
                        const int* __restrict__ bsum, int* __restrict__ start, int* __restrict__ cur) {
  int i = blockIdx.x * 256 + threadIdx.x;
  if (i >= NN) return;
  int b = i >> 8;
  int off = b ? bsum[b - 1] : 0;
  int excl = tmp[i] - deg[i] + off;
  start[i] = excl; cur[i] = excl;
}

__global__ void fill_k(const int* __restrict__ ei, int* __restrict__ cur,
                       int* __restrict__ csr_src, int* __restrict__ csr_dst,
                       const int* __restrict__ flags) {
  int e = blockIdx.x * 256 + threadIdx.x;
  if (e >= ETOT) return;
  int s, d; edge_sd(ei, e, flags[0], s, d);
  int pos = atomicAdd(&cur[d], 1);
  csr_src[pos] = s; csr_dst[pos] = d;
}

// ================= GEMM1 path A: 256x256 tile, BK=32, 8 waves (2x4),
// double-buffered global_load_lds (R11-proven), chunk-XOR swizzle,
// fused att1 partials, coalesced C-store via LDS round-trip.
__global__ __launch_bounds__(512) void gemm1c_k(const u16* __restrict__ xb,
                                                const u16* __restrict__ w1t,
                                                u16* __restrict__ h1,
                                                const float* __restrict__ as1c,
                                                const float* __restrict__ ad1c,
                                                float* __restrict__ a_s1,
                                                float* __restrict__ a_d1) {
  __shared__ u16 As[2 * 8192];   // [buf][256 rows][32 k] = 32 KB (reused as Cs in epilogue)
  __shared__ u16 Bs[2 * 8192];
  const int t = threadIdx.x;
  const int lane = t & 63, wid = t >> 6;   // 8 waves
  const int wr = wid >> 2, wc = wid & 3;   // 2 x 4 wave grid, wave tile 128x64
  const int m0 = blockIdx.y * 256, n0 = blockIdx.x * 256;
  const int l16 = lane & 15;
  f32x4 acc[8][4];
  #pragma unroll
  for (int i = 0; i < 8; ++i)
    #pragma unroll
    for (int j = 0; j < 4; ++j) acc[i][j] = (f32x4){0.f, 0.f, 0.f, 0.f};

  const int kc = ((t & 3) ^ ((t >> 3) & 3)) * 8;
  const size_t sa0 = (size_t)(m0 + (t >> 2)) * KP + kc;
  const size_t sa1 = sa0 + (size_t)128 * KP;
  const size_t sb0 = (size_t)(n0 + (t >> 2)) * KP + kc;
  const size_t sb1 = sb0 + (size_t)128 * KP;

  const int fsw = ((lane >> 4) ^ ((l16 >> 1) & 3)) << 3;
  const int rdA = (wr * 128 + l16) * 32 + fsw;   // + mi*512
  const int rdB = (wc * 64 + l16) * 32 + fsw;    // + ni*512

#define STAGE(K0, B) do {                                  \
    u16* a_ = As + (B) * 8192 + (wid << 9);                \
    u16* b_ = Bs + (B) * 8192 + (wid << 9);                \
    gl_lds16(xb  + sa0 + (K0), a_);                        \
    gl_lds16(xb  + sa1 + (K0), a_ + 4096);                 \
    gl_lds16(w1t + sb0 + (K0), b_);                        \
    gl_lds16(w1t + sb1 + (K0), b_ + 4096);                 \
  } while (0)

  STAGE(0, 0);
  __syncthreads();
  int cur = 0;
  for (int k0 = 0; k0 < KP; k0 += 32) {
    if (k0 + 32 < KP) STAGE(k0 + 32, cur ^ 1);   // prefetch next K-tile
    const u16* Ab = As + cur * 8192;
    const u16* Bb = Bs + cur * 8192;
    bf16x8 bfr[4];
    #pragma unroll
    for (int ni = 0; ni < 4; ++ni)
      bfr[ni] = *(const bf16x8*)&Bb[rdB + ni * 512];
    #pragma unroll
    for (int mi = 0; mi < 8; ++mi) {
      bf16x8 af = *(const bf16x8*)&Ab[rdA + mi * 512];
      #pragma unroll
      for (int ni = 0; ni < 4; ++ni)
        acc[mi][ni] = __builtin_amdgcn_mfma_f32_16x16x32_bf16(af, bfr[ni], acc[mi][ni], 0, 0, 0);
    }
    __syncthreads();   // next stage landed; cur reads done
    cur ^= 1;
  }
#undef STAGE

  // ---- fused att1: per-row weighted col sums -> shfl reduce -> atomic partials
  const int h0 = n0 >> 8;          // head of this col tile (N-tile == C1)
  const int lr4 = (lane >> 4) * 4;
  #pragma unroll
  for (int mi = 0; mi < 8; ++mi) {
    float ps[4] = {0.f, 0.f, 0.f, 0.f}, pd[4] = {0.f, 0.f, 0.f, 0.f};
    #pragma unroll
    for (int ni = 0; ni < 4; ++ni) {
      int col = n0 + wc * 64 + ni * 16 + l16;
      float wsv = as1c[col], wdv = ad1c[col];
      #pragma unroll
      for (int r = 0; r < 4; ++r) {
        float v = acc[mi][ni][r];
        ps[r] += v * wsv;
        pd[r] += v * wdv;
      }
    }
    #pragma unroll
    for (int o = 1; o < 16; o <<= 1) {
      #pragma unroll
      for (int r = 0; r < 4; ++r) {
        ps[r] += __shfl_xor(ps[r], o, 64);
        pd[r] += __shfl_xor(pd[r], o, 64);
      }
    }
    if (l16 == 0) {
      int rowb = m0 + wr * 128 + mi * 16 + lr4;
      #pragma unroll
      for (int r = 0; r < 4; ++r) {
        int row = rowb + r;
        if (row < NN) {
          atomicAdd(&a_s1[row * NH1 + h0], ps[r]);
          atomicAdd(&a_d1[row * NH1 + h0], pd[r]);
        }
      }
    }
  }

  // ---- C store via LDS (coalesced): 8 passes of 32 rows; Cs reuses As (16.9 KB)
  u16* Cs = As;
  const int rrow = t >> 4;          // 0..31 LDS row
  const int rchk = t & 15;          // 16-u16 (32B) chunk within row
  for (int mi = 0; mi < 8; ++mi) {
    __syncthreads();               // previous pass readback done
    #pragma unroll
    for (int ni = 0; ni < 4; ++ni)
      #pragma unroll
      for (int r = 0; r < 4; ++r)
        Cs[(wr * 16 + lr4 + r) * CSS + wc * 64 + ni * 16 + l16] = f2bf(acc[mi][ni][r]);
    __syncthreads();
    int grow = m0 + (rrow >> 4) * 128 + mi * 16 + (rrow & 15);
    if (grow < NN) {
      const uint4* src = (const uint4*)&Cs[rrow * CSS + rchk * 16];
      uint4 v0 = src[0], v1 = src[1];
      uint4* dst = (uint4*)&h1[(size_t)grow * F1 + n0 + rchk * 16];
      dst[0] = v0; dst[1] = v1;
    }
  }
}

// ================= GEMM1 path B (fallback, reg-staged, dual-dtype) =================
__global__ __launch_bounds__(256) void gemm1m_k(const void* __restrict__ xv,
                                                const u16* __restrict__ w1t,
                                                u16* __restrict__ h1,
                                                const int* __restrict__ flags) {
  __shared__ u16 As[128][40];
  __shared__ u16 Bs[128][40];
  const int fm = flags[1];
  const int t = threadIdx.x;
  const int lane = t & 63, wid = t >> 6;
  const int wr = wid >> 1, wc = wid & 1;
  const int m0 = blockIdx.y * 128, n0 = blockIdx.x * 128;
  const int l16 = lane & 15, lk = (lane >> 4) * 8;
  f32x4 acc[4][4];
  #pragma unroll
  for (int i = 0; i < 4; ++i)
    #pragma unroll
    for (int j = 0; j < 4; ++j) acc[i][j] = (f32x4){0.f, 0.f, 0.f, 0.f};
  const int arow = t >> 2;
  const int akb  = (t & 3) * 8;
  for (int k0 = 0; k0 < KP; k0 += 32) {
    #pragma unroll
    for (int i = 0; i < 2; ++i) {
      int row = arow + i * 64;
      int rg = m0 + row;
      u32 d0 = 0, d1 = 0, d2 = 0, d3 = 0;
      if (rg < NN) {
        if (k0 + 32 <= FIN) {
          if (fm) {
            const float* xp = (const float*)xv + (size_t)rg * FIN + k0 + akb;
            float2 p0 = *(const float2*)(xp);
            float2 p1 = *(const float2*)(xp + 2);
            float2 p2 = *(const float2*)(xp + 4);
            float2 p3 = *(const float2*)(xp + 6);
            d0 = (u32)f2bf(p0.x) | ((u32)f2bf(p0.y) << 16);
            d1 = (u32)f2bf(p1.x) | ((u32)f2bf(p1.y) << 16);
            d2 = (u32)f2bf(p2.x) | ((u32)f2bf(p2.y) << 16);
            d3 = (u32)f2bf(p3.x) | ((u32)f2bf(p3.y) << 16);
          } else {
            const u16* xp = (const u16*)xv + (size_t)rg * FIN + k0 + akb;
            d0 = *(const u32*)(xp);
            d1 = *(const u32*)(xp + 2);
            d2 = *(const u32*)(xp + 4);
            d3 = *(const u32*)(xp + 6);
          }
        } else {
          u16 e[8];
          #pragma unroll
          for (int q = 0; q < 8; ++q) {
            int k = k0 + akb + q;
            e[q] = 0;
            if (k < FIN)
              e[q] = fm ? f2bf(((const float*)xv)[(size_t)rg * FIN + k])
                        : ((const u16*)xv)[(size_t)rg * FIN + k];
          }
          d0 = (u32)e[0] | ((u32)e[1] << 16);
          d1 = (u32)e[2] | ((u32)e[3] << 16);
          d2 = (u32)e[4] | ((u32)e[5] << 16);
          d3 = (u32)e[6] | ((u32)e[7] << 16);
        }
      }
      *(uint4*)&As[row][akb] = make_uint4(d0, d1, d2, d3);
      const u16* wp = w1t + (size_t)(n0 + row) * KP + k0 + akb;
      *(uint4*)&Bs[row][akb] = *(const uint4*)wp;
    }
    __syncthreads();
    bf16x8 bfr[4];
    #pragma unroll
    for (int ni = 0; ni < 4; ++ni)
      bfr[ni] = *(const bf16x8*)&Bs[wc * 64 + ni * 16 + l16][lk];
    #pragma unroll
    for (int mi = 0; mi < 4; ++mi) {
      bf16x8 af = *(const bf16x8*)&As[wr * 64 + mi * 16 + l16][lk];
      #pragma unroll
      for (int ni = 0; ni < 4; ++ni)
        acc[mi][ni] = __builtin_amdgcn_mfma_f32_16x16x32_bf16(af, bfr[ni], acc[mi][ni], 0, 0, 0);
    }
    __syncthreads();
  }
  const int lr4 = (lane >> 4) * 4;
  #pragma unroll
  for (int mi = 0; mi < 4; ++mi) {
    #pragma unroll
    for (int r = 0; r < 4; ++r) {
      int row = m0 + wr * 64 + mi * 16 + lr4 + r;
      if (row < NN) {
        #pragma unroll
        for (int ni = 0; ni < 4; ++ni) {
          int col = n0 + wc * 64 + ni * 16 + l16;
          h1[(size_t)row * F1 + col] = f2bf(acc[mi][ni][r]);
        }
      }
    }
  }
}

// ================= attention scalars (fallback path only)
__global__ __launch_bounds__(256) void att1_k(const u16* __restrict__ h1,
                                              const float* __restrict__ as1c, const float* __restrict__ ad1c,
                                              float* __restrict__ a_s, float* __restrict__ a_d) {
  int n = blockIdx.x, t = threadIdx.x;
  int h = t >> 5, l = t & 31;
  int base = h * C1 + l * 8;
  const u16* hp = h1 + (size_t)n * F1 + base;
  uint4 v = *(const uint4*)hp;
  u32 w[4] = {v.x, v.y, v.z, v.w};
  float ss = 0.f, sd = 0.f;
  #pragma unroll
  for (int p = 0; p < 4; ++p) {
    float e0 = bflo(w[p]), e1 = bfhi(w[p]);
    ss += e0 * as1c[base + 2*p] + e1 * as1c[base + 2*p + 1];
    sd += e0 * ad1c[base + 2*p] + e1 * ad1c[base + 2*p + 1];
  }
  #pragma unroll
  for (int o = 16; o > 0; o >>= 1) {
    ss += __shfl_down(ss, o, 32);
    sd += __shfl_down(sd, o, 32);
  }
  if (l == 0) { a_s[n * NH1 + h] = ss; a_d[n * NH1 + h] = sd; }
}

// ================= fused: gather+bias+ReLU -> LDS -> MFMA @ w2t -> h2 + fused att2
// 512 threads: two 256-thread halves each gather 8 of the block's 16 nodes.
// Phase B: 8 waves = 4 col-groups x 2 K-halves, LDS partial reduce; att2 partials
// computed from final h2 registers (kills the 40000-block att2_k launch).
__global__ __launch_bounds__(512) void gfuse_k(const int* __restrict__ start, const int* __restrict__ deg,
                                               const int* __restrict__ csr_src,
                                               const float* __restrict__ a_s1, const float* __restrict__ a_d1,
                                               const u16* __restrict__ h1, const float* __restrict__ b1c,
                                               const u16* __restrict__ w2t,
                                               const float* __restrict__ as2c, const float* __restrict__ ad2c,
                                               float* __restrict__ h2,
                                               float* __restrict__ a_s2, float* __restrict__ a_d2) {
  __shared__ u16 rowsL[16 * F1];   // 64 KB
  __shared__ float pb[4][16][16];  // 4 KB K-half partials
  int t = threadIdx.x;
  int nb = blockIdx.x * 16;
  int sub = t & 255, grp = t >> 8;
  int h = sub >> 5;
  int c0 = sub * 8;
  float4 bA = *(const float4*)(b1c + c0);
  float4 bB = *(const float4*)(b1c + c0 + 4);
  for (int ii = 0; ii < 8; ++ii) {
    int i = grp * 8 + ii;
    int n = nb + i;
    int s0 = start[n], jend = s0 + deg[n];
    float ad = a_d1[n * NH1 + h];
    float a0=0.f,a1=0.f,a2=0.f,a3=0.f,a4=0.f,a5=0.f,a6=0.f,a7=0.f,den=0.f;
    int j = s0;
    for (; j + 2 <= jend; j += 2) {
      int sA = csr_src[j], sB = csr_src[j + 1];
      float vA = a_s1[sA * NH1 + h] + ad;
      float vB = a_s1[sB * NH1 + h] + ad;
      vA = vA > 0.f ? vA : NEG * vA;
      vB = vB > 0.f ? vB : NEG * vB;
      float eA = expf(vA), eB = expf(vB);
      uint4 uA = *(const uint4*)(h1 + (size_t)sA * F1 + c0);
      uint4 uB = *(const uint4*)(h1 + (size_t)sB * F1 + c0);
      den += eA + eB;
      a0 += eA * bflo(uA.x) + eB * bflo(uB.x);
      a1 += eA * bfhi(uA.x) + eB * bfhi(uB.x);
      a2 += eA * bflo(uA.y) + eB * bflo(uB.y);
      a3 += eA * bfhi(uA.y) + eB * bfhi(uB.y);
      a4 += eA * bflo(uA.z) + eB * bflo(uB.z);
      a5 += eA * bfhi(uA.z) + eB * bfhi(uB.z);
      a6 += eA * bflo(uA.w) + eB * bflo(uB.w);
      a7 += eA * bfhi(uA.w) + eB * bfhi(uB.w);
    }
    if (j < jend) {
      int sA = csr_src[j];
      float vA = a_s1[sA * NH1 + h] + ad;
      vA = vA > 0.f ? vA : NEG * vA;
      float eA = expf(vA);
      uint4 uA = *(const uint4*)(h1 + (size_t)sA * F1 + c0);
      den += eA;
      a0 += eA * bflo(uA.x); a1 += eA * bfhi(uA.x);
      a2 += eA * bflo(uA.y); a3 += eA * bfhi(uA.y);
      a4 += eA * bflo(uA.z); a5 += eA * bfhi(uA.z);
      a6 += eA * bflo(uA.w); a7 += eA * bfhi(uA.w);
    }
    float inv = 1.f / (den + 1e-16f);
    u16 o0 = f2bf(fmaxf(a0 * inv + bA.x, 0.f));
    u16 o1 = f2bf(fmaxf(a1 * inv + bA.y, 0.f));
    u16 o2 = f2bf(fmaxf(a2 * inv + bA.z, 0.f));
    u16 o3 = f2bf(fmaxf(a3 * inv + bA.w, 0.f));
    u16 o4 = f2bf(fmaxf(a4 * inv + bB.x, 0.f));
    u16 o5 = f2bf(fmaxf(a5 * inv + bB.y, 0.f));
    u16 o6 = f2bf(fmaxf(a6 * inv + bB.z, 0.f));
    u16 o7 = f2bf(fmaxf(a7 * inv + bB.w, 0.f));
    uint4 pk;
    pk.x = (u32)o0 | ((u32)o1 << 16);
    pk.y = (u32)o2 | ((u32)o3 << 16);
    pk.z = (u32)o4 | ((u32)o5 << 16);
    pk.w = (u32)o6 | ((u32)o7 << 16);
    int sw = (i & 7) << 3;
    *(uint4*)&rowsL[i * F1 + (c0 ^ sw)] = pk;
  }
  __syncthreads();
  // phase B: C[16 nodes][64 cols] = rowsL @ w2t^T; wave = (col-group g, K-half kh)
  int lane = t & 63, wid = t >> 6;       // 8 waves
  int g = wid & 3, kh = wid >> 2;
  int l16 = lane & 15, lk = (lane >> 4) * 8;
  const u16* wt = w2t + (size_t)(g * 16 + l16) * F1;
  int sw = (l16 & 7) << 3;
  f32x4 acc2 = (f32x4){0.f, 0.f, 0.f, 0.f};
  const int kbase = kh * (F1 / 2);
  for (int k0 = 0; k0 < F1 / 2; k0 += 32) {
    int kk = kbase + k0 + lk;
    bf16x8 af = *(const bf16x8*)&rowsL[l16 * F1 + (kk ^ sw)];
    bf16x8 bf = *(const bf16x8*)(wt + kk);
    acc2 = __builtin_amdgcn_mfma_f32_16x16x32_bf16(af, bf, acc2, 0, 0, 0);
  }
  int mb = (lane >> 4) * 4;
  if (kh == 1) {
    #pragma unroll
    for (int r = 0; r < 4; ++r) pb[g][mb + r][l16] = acc2[r];
  }
  __syncthreads();
  if (kh == 0) {
    int col = g * 16 + l16;
    float vals[4];
    #pragma unroll
    for (int r = 0; r < 4; ++r) vals[r] = acc2[r] + pb[g][mb + r][l16];
    if (col < C2) {
      #pragma unroll
      for (int r = 0; r < 4; ++r)
        h2[(size_t)(nb + mb + r) * C2 + col] = vals[r];
    }
    // fused att2: per-row dot with as2/ad2, reduce over 16-lane col group
    float as2v = (col < C2) ? as2c[col] : 0.f;
    float ad2v = (col < C2) ? ad2c[col] : 0.f;
    float ps[4], pd[4];
    #pragma unroll
    for (int r = 0; r < 4; ++r) { ps[r] = vals[r] * as2v; pd[r] = vals[r] * ad2v; }
    #pragma unroll
    for (int o = 1; o < 16; o <<= 1) {
      #pragma unroll
      for (int r = 0; r < 4; ++r) {
        ps[r] += __shfl_xor(ps[r], o, 64);
        pd[r] += __shfl_xor(pd[r], o, 64);
      }
    }
    if (l16 == 0 && g < 3) {   // g==3 cols are all >= C2 (zero contribution)
      #pragma unroll
      for (int r = 0; r < 4; ++r) {
        atomicAdd(&a_s2[nb + mb + r], ps[r]);
        atomicAdd(&a_d2[nb + mb + r], pd[r]);
      }
    }
  }
}

// ================= layer-2 gather + bias + log_softmax, 4 nodes/block
__global__ __launch_bounds__(256) void gath2_k(const int* __restrict__ start, const int* __restrict__ deg,
                                               const int* __restrict__ csr_src,
                                               const float* __restrict__ a_s, const float* __restrict__ a_d,
                                               const float* __restrict__ h2, const float* __restrict__ b2,
                                               void* __restrict__ outv, const int* __restrict__ flags) {
  int w = threadIdx.x >> 6, lane = threadIdx.x & 63;
  int n = blockIdx.x * 4 + w;
  int s0 = start[n], cnt = deg[n];
  float ad = a_d[n];
  float acc = 0.f, den = 0.f;
  for (int j = s0; j < s0 + cnt; ++j) {
    int s = csr_src[j];
    float v = a_s[s] + ad;
    v = v > 0.f ? v : NEG * v;
    float e = expf(v);
    den += e;
    if (lane < C2) acc += e * h2[(size_t)s * C2 + lane];
  }
  float raw = (lane < C2) ? acc / (den + 1e-16f) + b2[lane] : -1e30f;
  float m = raw;
  #pragma unroll
  for (int o = 32; o > 0; o >>= 1) m = fmaxf(m, __shfl_down(m, o, 64));
  m = __shfl(m, 0, 64);
  float e2 = (lane < C2) ? expf(raw - m) : 0.f;
  float ssum = e2;
  #pragma unroll
  for (int o = 32; o > 0; o >>= 1) ssum += __shfl_down(ssum, o, 64);
  ssum = __shfl(ssum, 0, 64);
  if (lane < C2) {
    float v = raw - m - logf(ssum);
    if (flags[1]) ((float*)outv)[(size_t)n * C2 + lane] = v;
    else          ((u16*) outv)[(size_t)n * C2 + lane] = f2bf(v);
  }
}

extern "C" void kernel_launch(void* const* d_in, const int* in_sizes, int n_in,
                              void* d_out, int out_size, void* d_ws, size_t ws_size,
                              hipStream_t stream) {
  const void* x   = d_in[0];
  const int*  ei  = (const int*)d_in[1];
  const void* W1  = d_in[2];
  const void* as1 = d_in[3];
  const void* ad1 = d_in[4];
  const void* b1  = d_in[5];
  const void* W2  = d_in[6];
  const void* as2 = d_in[7];
  const void* ad2 = d_in[8];
  const void* b2  = d_in[9];

  char* ws = (char*)d_ws;
  u16*   h1      = (u16*)  (ws);                  // 163,840,000
  float* h2      = (float*)(ws + 163840000);      //   6,720,000
  float* a_s1    = (float*)(ws + 170560000);      //   1,280,000
  float* a_d1    = (float*)(ws + 171840000);      //   1,280,000
  float* a_s2    = (float*)(ws + 173120000);      //     160,000
  float* a_d2    = (float*)(ws + 173280000);      //     160,000
  int*   deg     = (int*)  (ws + 173440000);      //     160,000
  int*   start   = (int*)  (ws + 173600000);      //     160,000
  int*   cur     = (int*)  (ws + 173760000);      //     160,000
  int*   tmp     = (int*)  (ws + 173920000);      //     160,000
  int*   csr_src = (int*)  (ws + 174080000);      //     800,000
  int*   csr_dst = (int*)  (ws + 174880000);      //     800,000
  int*   bsum    = (int*)  (ws + 175680000);      //       1,024
  u16*   w1t     = (u16*)  (ws + 175681024);      //   2,490,368
  u16*   w2t     = (u16*)  (ws + 178171392);      //     262,144
  float* as1c    = (float*)(ws + 178433536);      //       8,192
  float* ad1c    = (float*)(ws + 178441728);      //       8,192
  float* b1c     = (float*)(ws + 178449920);      //       8,192
  float* as2c    = (float*)(ws + 178458112);      //         256
  float* ad2c    = (float*)(ws + 178458368);      //         256
  float* b2c     = (float*)(ws + 178458624);      //         256
  int*   flags   = (int*)  (ws + 178458880);      //         256
  const size_t TOTAL_BASE = 178459136;
  u16*   xb      = (u16*)  (ws + TOTAL_BASE);     //  48,873,472 (path A only)
  const size_t TOTAL_A = TOTAL_BASE + (size_t)MP * KP * 2;  // 227,332,608 (< proven 233.6MB)
  if (ws_size < TOTAL_BASE) return;
  const bool pathA = (ws_size >= TOTAL_A);

  probe_k<<<1, 64, 0, stream>>>((const u32*)x, ei, flags);

  cvt_all_k<<<(F1 + 255) / 256, 256, 0, stream>>>(as1, ad1, b1, as2, ad2, b2,
                                                  as1c, ad1c, b1c, as2c, ad2c, b2c, flags);
  w1t_k<<<dim3(8, KP), 256, 0, stream>>>(W1, w1t, flags);
  w2t_k<<<(64 * F1 + 255) / 256, 256, 0, stream>>>(W2, w2t, flags);

  hipMemsetAsync(deg, 0, NN * sizeof(int), stream);
  // a_s1, a_d1, a_s2, a_d2 are contiguous: zero all four (gemm1c + gfuse atomics)
  hipMemsetAsync(a_s1, 0, (2 * NN * NH1 + 2 * NN) * sizeof(float), stream);
  const int EB = (ETOT + 255) / 256;
  deg_k  <<<EB, 256, 0, stream>>>(ei, deg, flags);
  scan1_k<<<NB, 256, 0, stream>>>(deg, tmp, bsum);
  scan2_k<<<1, 256, 0, stream>>>(bsum);
  scan3_k<<<NB, 256, 0, stream>>>(deg, tmp, bsum, start, cur);
  fill_k <<<EB, 256, 0, stream>>>(ei, cur, csr_src, csr_dst, flags);

  if (pathA) {
    xb_k<<<dim3((KP + 255) / 256, MP), 256, 0, stream>>>(x, xb, flags);
    gemm1c_k<<<dim3(8, MP / 256), 512, 0, stream>>>(xb, w1t, h1, as1c, ad1c, a_s1, a_d1);
  } else {
    gemm1m_k<<<dim3(16, 313), 256, 0, stream>>>(x, w1t, h1, flags);
    att1_k<<<NN, 256, 0, stream>>>(h1, as1c, ad1c, a_s1, a_d1);
  }
  gfuse_k<<<NN / 16, 512, 0, stream>>>(start, deg, csr_src, a_s1, a_d1, h1, b1c, w2t,
                                       as2c, ad2c, h2, a_s2, a_d2);

  gath2_k<<<NN / 4, 256, 0, stream>>>(start, deg, csr_src, a_s2, a_d2, h2, b2c, d_out, flags);
}

// Round 14
// 618.296 us; speedup vs baseline: 1.1049x; 1.0077x over previous
//
#include <hip/hip_runtime.h>
#include <hip/hip_bf16.h>

#define NN   40000
#define NE   160000
#define ETOT 200000   // NE + NN self loops
#define FIN  602
#define NH1  8
#define C1   256
#define F1   2048     // NH1*C1
#define C2   42
#define NEG  0.2f
#define NB   157      // ceil(NN/256)
#define KP   608      // FIN padded to mult of 32
#define MP   40192    // NN padded to mult of 256 (157*256)
#define CSS  264      // Cs LDS row stride (u16), padded vs 256 to spread banks

typedef unsigned short u16;
typedef unsigned int   u32;
typedef __bf16 bf16x8 __attribute__((ext_vector_type(8)));
typedef float  f32x4  __attribute__((ext_vector_type(4)));

__device__ __forceinline__ float bfu(u16 v){ return __uint_as_float(((u32)v) << 16); }
__device__ __forceinline__ float bflo(u32 u){ return __uint_as_float(u << 16); }
__device__ __forceinline__ float bfhi(u32 u){ return __uint_as_float(u & 0xffff0000u); }
__device__ __forceinline__ u16 f2bf(float f){
  u32 u = __float_as_uint(f);
  u32 r = (u + 0x7fffu + ((u >> 16) & 1u)) >> 16;   // RNE
  return (u16)r;
}

// async global->LDS, 16B per lane; LDS dest = wave-uniform base + lane*16
__device__ __forceinline__ void gl_lds16(const u16* g, u16* l) {
  __builtin_amdgcn_global_load_lds(
      (const __attribute__((address_space(1))) u32*)(g),
      (__attribute__((address_space(3))) u32*)(l), 16, 0, 0);
}

// ================= dtype probe =================
__global__ void probe_k(const u32* __restrict__ xw, const int* __restrict__ ei,
                        int* __restrict__ flags) {
  if (threadIdx.x == 0) {
    int zc = 0;
    for (int k = 0; k < 64; ++k) zc += (ei[2*k + 1] == 0) ? 1 : 0;
    flags[0] = (zc == 64) ? 1 : 0;
    int inr = 0;
    for (int k = 0; k < 64; ++k) {
      u32 low = xw[k] & 0xffffu;
      int e = (int)((low >> 7) & 0xff);
      inr += (e >= 100 && e <= 140) ? 1 : 0;
    }
    flags[1] = (inr >= 32) ? 0 : 1;
  }
}

// all small f32 canonicalizations in one launch
__global__ void cvt_all_k(const void* __restrict__ as1, const void* __restrict__ ad1,
                          const void* __restrict__ b1,  const void* __restrict__ as2,
                          const void* __restrict__ ad2, const void* __restrict__ b2,
                          float* __restrict__ as1c, float* __restrict__ ad1c,
                          float* __restrict__ b1c,  float* __restrict__ as2c,
                          float* __restrict__ ad2c, float* __restrict__ b2c,
                          const int* __restrict__ flags) {
  int i = blockIdx.x * 256 + threadIdx.x;
  int fm = flags[1];
  if (i < F1) {
    as1c[i] = fm ? ((const float*)as1)[i] : bfu(((const u16*)as1)[i]);
    ad1c[i] = fm ? ((const float*)ad1)[i] : bfu(((const u16*)ad1)[i]);
    b1c[i]  = fm ? ((const float*)b1)[i]  : bfu(((const u16*)b1)[i]);
  }
  if (i < C2) {
    as2c[i] = fm ? ((const float*)as2)[i] : bfu(((const u16*)as2)[i]);
    ad2c[i] = fm ? ((const float*)ad2)[i] : bfu(((const u16*)ad2)[i]);
    b2c[i]  = fm ? ((const float*)b2)[i]  : bfu(((const u16*)b2)[i]);
  }
}

// xb[MP][KP] = x as bf16, zero-padded rows/cols; 4 elems/thread, 192 thr/row
__global__ __launch_bounds__(192) void xb4_k(const void* __restrict__ x, u16* __restrict__ xb,
                                             const int* __restrict__ flags) {
  int t = threadIdx.x;
  if (t >= 152) return;            // 152*4 = 608 = KP
  int row = blockIdx.x;
  int k0 = t * 4;
  ushort4 o = make_ushort4(0, 0, 0, 0);
  if (row < NN) {
    if (k0 + 4 <= FIN) {
      if (flags[1]) {
        const float* xp = (const float*)x + (size_t)row * FIN + k0;  // 8B aligned
        float2 p0 = *(const float2*)(xp);
        float2 p1 = *(const float2*)(xp + 2);
        o.x = f2bf(p0.x); o.y = f2bf(p0.y); o.z = f2bf(p1.x); o.w = f2bf(p1.y);
      } else {
        const u16* xp = (const u16*)x + (size_t)row * FIN + k0;      // 4B aligned
        u32 p0 = *(const u32*)(xp);
        u32 p1 = *(const u32*)(xp + 2);
        o.x = (u16)(p0 & 0xffff); o.y = (u16)(p0 >> 16);
        o.z = (u16)(p1 & 0xffff); o.w = (u16)(p1 >> 16);
      }
    } else {
      u16 e[4] = {0, 0, 0, 0};
      for (int q = 0; q < 4; ++q) {
        int k = k0 + q;
        if (k < FIN)
          e[q] = flags[1] ? f2bf(((const float*)x)[(size_t)row * FIN + k])
                          : ((const u16*)x)[(size_t)row * FIN + k];
      }
      o = make_ushort4(e[0], e[1], e[2], e[3]);
    }
  }
  *(ushort4*)(xb + (size_t)row * KP + k0) = o;   // 8B aligned
}

// W1t[n][k] = W1[k][n], k padded to 608 with zeros. bf16.
__global__ void w1t_k(const void* __restrict__ W1, u16* __restrict__ w1t,
                      const int* __restrict__ flags) {
  int n = blockIdx.x * 256 + threadIdx.x;
  int k = blockIdx.y;
  if (n >= F1) return;
  u16 v = 0;
  if (k < FIN) v = flags[1] ? f2bf(((const float*)W1)[(size_t)k * F1 + n])
                            : ((const u16*)W1)[(size_t)k * F1 + n];
  w1t[(size_t)n * KP + k] = v;
}

// w2t[c][k] = W2[k][c], c padded 42->64 with zeros. bf16.
__global__ void w2t_k(const void* __restrict__ W2, u16* __restrict__ w2t,
                      const int* __restrict__ flags) {
  int i = blockIdx.x * 256 + threadIdx.x;
  if (i >= 64 * F1) return;
  int c = i >> 11, k = i & (F1 - 1);
  u16 v = 0;
  if (c < C2) v = flags[1] ? f2bf(((const float*)W2)[(size_t)k * C2 + c])
                           : ((const u16*)W2)[(size_t)k * C2 + c];
  w2t[i] = v;
}

// ================= CSR build =================
__device__ __forceinline__ void edge_sd(const int* __restrict__ ei, int e, int imode,
                                        int& s, int& d) {
  if (e < NE) {
    if (imode) { s = ei[2*e]; d = ei[2*(NE + e)]; }
    else       { s = ei[e];   d = ei[NE + e];     }
  } else { s = d = e - NE; }
}

__global__ void deg_k(const int* __restrict__ ei, int* __restrict__ deg,
                      const int* __restrict__ flags) {
  int e = blockIdx.x * 256 + threadIdx.x;
  if (e >= ETOT) return;
  int s, d; edge_sd(ei, e, flags[0], s, d);
  atomicAdd(&deg[d], 1);
}

__global__ __launch_bounds__(256) void scan1_k(const int* __restrict__ deg,
                                               int* __restrict__ tmp, int* __restrict__ bsum) {
  __shared__ int s[256];
  int b = blockIdx.x, t = threadIdx.x, i = b * 256 + t;
  int v = (i < NN) ? deg[i] : 0;
  s[t] = v; __syncthreads();
  for (int o = 1; o < 256; o <<= 1) {
    int u = (t >= o) ? s[t - o] : 0;
    __syncthreads(); s[t] += u; __syncthreads();
  }
  if (i < NN) tmp[i] = s[t];
  if (t == 255) bsum[b] = s[255];
}

__global__ __launch_bounds__(256) void scan2_k(int* __restrict__ bsum) {
  __shared__ int s[256];
  int t = threadIdx.x;
  int v = (t < NB) ? bsum[t] : 0;
  s[t] = v; __syncthreads();
  for (int o = 1; o < 256; o <<= 1) {
    int u = (t >= o) ? s[t - o] : 0;
    __syncthreads(); s[t] += u; __syncthreads();
  }
  if (t < NB) bsum[t] = s[t];
}

__global__ void scan3_k(const int* __restrict__ deg, const int* __restrict__ tmp,
                        const int* __restrict__ bsum, int* __restrict__ start, int* __restrict__ cur) {
  int i = blockIdx.x * 256 + threadIdx.x;
  if (i >= NN) return;
  int b = i >> 8;
  int off = b ? bsum[b - 1] : 0;
  int excl = tmp[i] - deg[i] + off;
  start[i] = excl; cur[i] = excl;
}

__global__ void fill_k(const int* __restrict__ ei, int* __restrict__ cur,
                       int* __restrict__ csr_src, int* __restrict__ csr_dst,
                       const int* __restrict__ flags) {
  int e = blockIdx.x * 256 + threadIdx.x;
  if (e >= ETOT) return;
  int s, d; edge_sd(ei, e, flags[0], s, d);
  int pos = atomicAdd(&cur[d], 1);
  csr_src[pos] = s; csr_dst[pos] = d;
}

// ================= GEMM1 path A: 256x256 tile, BK=32, 8 waves (2x4),
// 3-buffer LDS ring, depth-2 prefetch with COUNTED vmcnt + raw barriers
// (no sched_barrier pins - R12's mistake). Fused att1, coalesced C-store.
__global__ __launch_bounds__(512) void gemm1c_k(const u16* __restrict__ xb,
                                                const u16* __restrict__ w1t,
                                                u16* __restrict__ h1,
                                                const float* __restrict__ as1c,
                                                const float* __restrict__ ad1c,
                                                float* __restrict__ a_s1,
                                                float* __restrict__ a_d1) {
  __shared__ u16 As[3 * 8192];   // 48 KB (ring of 3; reused as Cs in epilogue)
  __shared__ u16 Bs[3 * 8192];   // 48 KB
  const int t = threadIdx.x;
  const int lane = t & 63, wid = t >> 6;   // 8 waves
  const int wr = wid >> 2, wc = wid & 3;   // 2 x 4 wave grid, wave tile 128x64
  const int m0 = blockIdx.y * 256, n0 = blockIdx.x * 256;
  const int l16 = lane & 15;
  f32x4 acc[8][4];
  #pragma unroll
  for (int i = 0; i < 8; ++i)
    #pragma unroll
    for (int j = 0; j < 4; ++j) acc[i][j] = (f32x4){0.f, 0.f, 0.f, 0.f};

  const int kc = ((t & 3) ^ ((t >> 3) & 3)) * 8;
  const size_t sa0 = (size_t)(m0 + (t >> 2)) * KP + kc;
  const size_t sa1 = sa0 + (size_t)128 * KP;
  const size_t sb0 = (size_t)(n0 + (t >> 2)) * KP + kc;
  const size_t sb1 = sb0 + (size_t)128 * KP;

  const int fsw = ((lane >> 4) ^ ((l16 >> 1) & 3)) << 3;
  const int rdA = (wr * 128 + l16) * 32 + fsw;   // + mi*512
  const int rdB = (wc * 64 + l16) * 32 + fsw;    // + ni*512

#define STAGE(K0, B) do {                                  \
    u16* a_ = As + (B) * 8192 + (wid << 9);                \
    u16* b_ = Bs + (B) * 8192 + (wid << 9);                \
    gl_lds16(xb  + sa0 + (K0), a_);                        \
    gl_lds16(xb  + sa1 + (K0), a_ + 4096);                 \
    gl_lds16(w1t + sb0 + (K0), b_);                        \
    gl_lds16(w1t + sb1 + (K0), b_ + 4096);                 \
  } while (0)

  STAGE(0, 0);
  STAGE(32, 1);
  int bi = 0;
  for (int k0 = 0; k0 < KP; k0 += 32) {
    const int steps_left = (KP - k0) >> 5;   // incl current: 19,18,...,1
    if (steps_left > 2) {
      int bn = bi + 2; bn = (bn >= 3) ? bn - 3 : bn;
      STAGE(k0 + 64, bn);                    // depth-2 prefetch
      asm volatile("s_waitcnt vmcnt(8)" ::: "memory");   // oldest tile (cur) landed
    } else if (steps_left == 2) {
      asm volatile("s_waitcnt vmcnt(4)" ::: "memory");
    } else {
      asm volatile("s_waitcnt vmcnt(0)" ::: "memory");
    }
    __builtin_amdgcn_s_barrier();            // all waves' cur-tile loads landed
    const u16* Ab = As + bi * 8192;
    const u16* Bb = Bs + bi * 8192;
    bf16x8 bfr[4];
    #pragma unroll
    for (int ni = 0; ni < 4; ++ni)
      bfr[ni] = *(const bf16x8*)&Bb[rdB + ni * 512];
    #pragma unroll
    for (int mi = 0; mi < 8; ++mi) {
      bf16x8 af = *(const bf16x8*)&Ab[rdA + mi * 512];
      #pragma unroll
      for (int ni = 0; ni < 4; ++ni)
        acc[mi][ni] = __builtin_amdgcn_mfma_f32_16x16x32_bf16(af, bfr[ni], acc[mi][ni], 0, 0, 0);
    }
    __builtin_amdgcn_s_barrier();            // reads of buf bi done chip-wide
    bi = bi + 1; bi = (bi >= 3) ? 0 : bi;
  }
#undef STAGE

  // ---- fused att1: per-row weighted col sums -> shfl reduce -> atomic partials
  const int h0 = n0 >> 8;          // head of this col tile (N-tile == C1)
  const int lr4 = (lane >> 4) * 4;
  #pragma unroll
  for (int mi = 0; mi < 8; ++mi) {
    float ps[4] = {0.f, 0.f, 0.f, 0.f}, pd[4] = {0.f, 0.f, 0.f, 0.f};
    #pragma unroll
    for (int ni = 0; ni < 4; ++ni) {
      int col = n0 + wc * 64 + ni * 16 + l16;
      float wsv = as1c[col], wdv = ad1c[col];
      #pragma unroll
      for (int r = 0; r < 4; ++r) {
        float v = acc[mi][ni][r];
        ps[r] += v * wsv;
        pd[r] += v * wdv;
      }
    }
    #pragma unroll
    for (int o = 1; o < 16; o <<= 1) {
      #pragma unroll
      for (int r = 0; r < 4; ++r) {
        ps[r] += __shfl_xor(ps[r], o, 64);
        pd[r] += __shfl_xor(pd[r], o, 64);
      }
    }
    if (l16 == 0) {
      int rowb = m0 + wr * 128 + mi * 16 + lr4;
      #pragma unroll
      for (int r = 0; r < 4; ++r) {
        int row = rowb + r;
        if (row < NN) {
          atomicAdd(&a_s1[row * NH1 + h0], ps[r]);
          atomicAdd(&a_d1[row * NH1 + h0], pd[r]);
        }
      }
    }
  }

  // ---- C store via LDS (coalesced): 8 passes of 32 rows; Cs reuses As (16.9 KB)
  u16* Cs = As;
  const int rrow = t >> 4;          // 0..31 LDS row
  const int rchk = t & 15;          // 16-u16 (32B) chunk within row
  for (int mi = 0; mi < 8; ++mi) {
    __syncthreads();               // previous pass readback done
    #pragma unroll
    for (int ni = 0; ni < 4; ++ni)
      #pragma unroll
      for (int r = 0; r < 4; ++r)
        Cs[(wr * 16 + lr4 + r) * CSS + wc * 64 + ni * 16 + l16] = f2bf(acc[mi][ni][r]);
    __syncthreads();
    int grow = m0 + (rrow >> 4) * 128 + mi * 16 + (rrow & 15);
    if (grow < NN) {
      const uint4* src = (const uint4*)&Cs[rrow * CSS + rchk * 16];
      uint4 v0 = src[0], v1 = src[1];
      uint4* dst = (uint4*)&h1[(size_t)grow * F1 + n0 + rchk * 16];
      dst[0] = v0; dst[1] = v1;
    }
  }
}

// ================= GEMM1 path B (fallback, reg-staged, dual-dtype) =================
__global__ __launch_bounds__(256) void gemm1m_k(const void* __restrict__ xv,
                                                const u16* __restrict__ w1t,
                                                u16* __restrict__ h1,
                                                const int* __restrict__ flags) {
  __shared__ u16 As[128][40];
  __shared__ u16 Bs[128][40];
  const int fm = flags[1];
  const int t = threadIdx.x;
  const int lane = t & 63, wid = t >> 6;
  const int wr = wid >> 1, wc = wid & 1;
  const int m0 = blockIdx.y * 128, n0 = blockIdx.x * 128;
  const int l16 = lane & 15, lk = (lane >> 4) * 8;
  f32x4 acc[4][4];
  #pragma unroll
  for (int i = 0; i < 4; ++i)
    #pragma unroll
    for (int j = 0; j < 4; ++j) acc[i][j] = (f32x4){0.f, 0.f, 0.f, 0.f};
  const int arow = t >> 2;
  const int akb  = (t & 3) * 8;
  for (int k0 = 0; k0 < KP; k0 += 32) {
    #pragma unroll
    for (int i = 0; i < 2; ++i) {
      int row = arow + i * 64;
      int rg = m0 + row;
      u32 d0 = 0, d1 = 0, d2 = 0, d3 = 0;
      if (rg < NN) {
        if (k0 + 32 <= FIN) {
          if (fm) {
            const float* xp = (const float*)xv + (size_t)rg * FIN + k0 + akb;
            float2 p0 = *(const float2*)(xp);
            float2 p1 = *(const float2*)(xp + 2);
            float2 p2 = *(const float2*)(xp + 4);
            float2 p3 = *(const float2*)(xp + 6);
            d0 = (u32)f2bf(p0.x) | ((u32)f2bf(p0.y) << 16);
            d1 = (u32)f2bf(p1.x) | ((u32)f2bf(p1.y) << 16);
            d2 = (u32)f2bf(p2.x) | ((u32)f2bf(p2.y) << 16);
            d3 = (u32)f2bf(p3.x) | ((u32)f2bf(p3.y) << 16);
          } else {
            const u16* xp = (const u16*)xv + (size_t)rg * FIN + k0 + akb;
            d0 = *(const u32*)(xp);
            d1 = *(const u32*)(xp + 2);
            d2 = *(const u32*)(xp + 4);
            d3 = *(const u32*)(xp + 6);
          }
        } else {
          u16 e[8];
          #pragma unroll
          for (int q = 0; q < 8; ++q) {
            int k = k0 + akb + q;
            e[q] = 0;
            if (k < FIN)
              e[q] = fm ? f2bf(((const float*)xv)[(size_t)rg * FIN + k])
                        : ((const u16*)xv)[(size_t)rg * FIN + k];
          }
          d0 = (u32)e[0] | ((u32)e[1] << 16);
          d1 = (u32)e[2] | ((u32)e[3] << 16);
          d2 = (u32)e[4] | ((u32)e[5] << 16);
          d3 = (u32)e[6] | ((u32)e[7] << 16);
        }
      }
      *(uint4*)&As[row][akb] = make_uint4(d0, d1, d2, d3);
      const u16* wp = w1t + (size_t)(n0 + row) * KP + k0 + akb;
      *(uint4*)&Bs[row][akb] = *(const uint4*)wp;
    }
    __syncthreads();
    bf16x8 bfr[4];
    #pragma unroll
    for (int ni = 0; ni < 4; ++ni)
      bfr[ni] = *(const bf16x8*)&Bs[wc * 64 + ni * 16 + l16][lk];
    #pragma unroll
    for (int mi = 0; mi < 4; ++mi) {
      bf16x8 af = *(const bf16x8*)&As[wr * 64 + mi * 16 + l16][lk];
      #pragma unroll
      for (int ni = 0; ni < 4; ++ni)
        acc[mi][ni] = __builtin_amdgcn_mfma_f32_16x16x32_bf16(af, bfr[ni], acc[mi][ni], 0, 0, 0);
    }
    __syncthreads();
  }
  const int lr4 = (lane >> 4) * 4;
  #pragma unroll
  for (int mi = 0; mi < 4; ++mi) {
    #pragma unroll
    for (int r = 0; r < 4; ++r) {
      int row = m0 + wr * 64 + mi * 16 + lr4 + r;
      if (row < NN) {
        #pragma unroll
        for (int ni = 0; ni < 4; ++ni) {
          int col = n0 + wc * 64 + ni * 16 + l16;
          h1[(size_t)row * F1 + col] = f2bf(acc[mi][ni][r]);
        }
      }
    }
  }
}

// ================= attention scalars (fallback path only)
__global__ __launch_bounds__(256) void att1_k(const u16* __restrict__ h1,
                                              const float* __restrict__ as1c, const float* __restrict__ ad1c,
                                              float* __restrict__ a_s, float* __restrict__ a_d) {
  int n = blockIdx.x, t = threadIdx.x;
  int h = t >> 5, l = t & 31;
  int base = h * C1 + l * 8;
  const u16* hp = h1 + (size_t)n * F1 + base;
  uint4 v = *(const uint4*)hp;
  u32 w[4] = {v.x, v.y, v.z, v.w};
  float ss = 0.f, sd = 0.f;
  #pragma unroll
  for (int p = 0; p < 4; ++p) {
    float e0 = bflo(w[p]), e1 = bfhi(w[p]);
    ss += e0 * as1c[base + 2*p] + e1 * as1c[base + 2*p + 1];
    sd += e0 * ad1c[base + 2*p] + e1 * ad1c[base + 2*p + 1];
  }
  #pragma unroll
  for (int o = 16; o > 0; o >>= 1) {
    ss += __shfl_down(ss, o, 32);
    sd += __shfl_down(sd, o, 32);
  }
  if (l == 0) { a_s[n * NH1 + h] = ss; a_d[n * NH1 + h] = sd; }
}

// ================= fused: gather+bias+ReLU -> LDS -> MFMA @ w2t -> h2 + fused att2
__global__ __launch_bounds__(512) void gfuse_k(const int* __restrict__ start, const int* __restrict__ deg,
                                               const int* __restrict__ csr_src,
                                               const float* __restrict__ a_s1, const float* __restrict__ a_d1,
                                               const u16* __restrict__ h1, const float* __restrict__ b1c,
                                               const u16* __restrict__ w2t,
                                               const float* __restrict__ as2c, const float* __restrict__ ad2c,
                                               float* __restrict__ h2,
                                               float* __restrict__ a_s2, float* __restrict__ a_d2) {
  __shared__ u16 rowsL[16 * F1];   // 64 KB
  __shared__ float pb[4][16][16];  // 4 KB K-half partials
  int t = threadIdx.x;
  int nb = blockIdx.x * 16;
  int sub = t & 255, grp = t >> 8;
  int h = sub >> 5;
  int c0 = sub * 8;
  float4 bA = *(const float4*)(b1c + c0);
  float4 bB = *(const float4*)(b1c + c0 + 4);
  for (int ii = 0; ii < 8; ++ii) {
    int i = grp * 8 + ii;
    int n = nb + i;
    int s0 = start[n], jend = s0 + deg[n];
    float ad = a_d1[n * NH1 + h];
    float a0=0.f,a1=0.f,a2=0.f,a3=0.f,a4=0.f,a5=0.f,a6=0.f,a7=0.f,den=0.f;
    int j = s0;
    for (; j + 2 <= jend; j += 2) {
      int sA = csr_src[j], sB = csr_src[j + 1];
      float vA = a_s1[sA * NH1 + h] + ad;
      float vB = a_s1[sB * NH1 + h] + ad;
      vA = vA > 0.f ? vA : NEG * vA;
      vB = vB > 0.f ? vB : NEG * vB;
      float eA = expf(vA), eB = expf(vB);
      uint4 uA = *(const uint4*)(h1 + (size_t)sA * F1 + c0);
      uint4 uB = *(const uint4*)(h1 + (size_t)sB * F1 + c0);
      den += eA + eB;
      a0 += eA * bflo(uA.x) + eB * bflo(uB.x);
      a1 += eA * bfhi(uA.x) + eB * bfhi(uB.x);
      a2 += eA * bflo(uA.y) + eB * bflo(uB.y);
      a3 += eA * bfhi(uA.y) + eB * bfhi(uB.y);
      a4 += eA * bflo(uA.z) + eB * bflo(uB.z);
      a5 += eA * bfhi(uA.z) + eB * bfhi(uB.z);
      a6 += eA * bflo(uA.w) + eB * bflo(uB.w);
      a7 += eA * bfhi(uA.w) + eB * bfhi(uB.w);
    }
    if (j < jend) {
      int sA = csr_src[j];
      float vA = a_s1[sA * NH1 + h] + ad;
      vA = vA > 0.f ? vA : NEG * vA;
      float eA = expf(vA);
      uint4 uA = *(const uint4*)(h1 + (size_t)sA * F1 + c0);
      den += eA;
      a0 += eA * bflo(uA.x); a1 += eA * bfhi(uA.x);
      a2 += eA * bflo(uA.y); a3 += eA * bfhi(uA.y);
      a4 += eA * bflo(uA.z); a5 += eA * bfhi(uA.z);
      a6 += eA * bflo(uA.w); a7 += eA * bfhi(uA.w);
    }
    float inv = 1.f / (den + 1e-16f);
    u16 o0 = f2bf(fmaxf(a0 * inv + bA.x, 0.f));
    u16 o1 = f2bf(fmaxf(a1 * inv + bA.y, 0.f));
    u16 o2 = f2bf(fmaxf(a2 * inv + bA.z, 0.f));
    u16 o3 = f2bf(fmaxf(a3 * inv + bA.w, 0.f));
    u16 o4 = f2bf(fmaxf(a4 * inv + bB.x, 0.f));
    u16 o5 = f2bf(fmaxf(a5 * inv + bB.y, 0.f));
    u16 o6 = f2bf(fmaxf(a6 * inv + bB.z, 0.f));
    u16 o7 = f2bf(fmaxf(a7 * inv + bB.w, 0.f));
    uint4 pk;
    pk.x = (u32)o0 | ((u32)o1 << 16);
    pk.y = (u32)o2 | ((u32)o3 << 16);
    pk.z = (u32)o4 | ((u32)o5 << 16);
    pk.w = (u32)o6 | ((u32)o7 << 16);
    int sw = (i & 7) << 3;
    *(uint4*)&rowsL[i * F1 + (c0 ^ sw)] = pk;
  }
  __syncthreads();
  // phase B: C[16 nodes][64 cols] = rowsL @ w2t^T; wave = (col-group g, K-half kh)
  int lane = t & 63, wid = t >> 6;       // 8 waves
  int g = wid & 3, kh = wid >> 2;
  int l16 = lane & 15, lk = (lane >> 4) * 8;
  const u16* wt = w2t + (size_t)(g * 16 + l16) * F1;
  int sw = (l16 & 7) << 3;
  f32x4 acc2 = (f32x4){0.f, 0.f, 0.f, 0.f};
  const int kbase = kh * (F1 / 2);
  for (int k0 = 0; k0 < F1 / 2; k0 += 32) {
    int kk = kbase + k0 + lk;
    bf16x8 af = *(const bf16x8*)&rowsL[l16 * F1 + (kk ^ sw)];
    bf16x8 bf = *(const bf16x8*)(wt + kk);
    acc2 = __builtin_amdgcn_mfma_f32_16x16x32_bf16(af, bf, acc2, 0, 0, 0);
  }
  int mb = (lane >> 4) * 4;
  if (kh == 1) {
    #pragma unroll
    for (int r = 0; r < 4; ++r) pb[g][mb + r][l16] = acc2[r];
  }
  __syncthreads();
  if (kh == 0) {
    int col = g * 16 + l16;
    float vals[4];
    #pragma unroll
    for (int r = 0; r < 4; ++r) vals[r] = acc2[r] + pb[g][mb + r][l16];
    if (col < C2) {
      #pragma unroll
      for (int r = 0; r < 4; ++r)
        h2[(size_t)(nb + mb + r) * C2 + col] = vals[r];
    }
    // fused att2: per-row dot with as2/ad2, reduce over 16-lane col group
    float as2v = (col < C2) ? as2c[col] : 0.f;
    float ad2v = (col < C2) ? ad2c[col] : 0.f;
    float ps[4], pd[4];
    #pragma unroll
    for (int r = 0; r < 4; ++r) { ps[r] = vals[r] * as2v; pd[r] = vals[r] * ad2v; }
    #pragma unroll
    for (int o = 1; o < 16; o <<= 1) {
      #pragma unroll
      for (int r = 0; r < 4; ++r) {
        ps[r] += __shfl_xor(ps[r], o, 64);
        pd[r] += __shfl_xor(pd[r], o, 64);
      }
    }
    if (l16 == 0 && g < 3) {   // g==3 cols are all >= C2 (zero contribution)
      #pragma unroll
      for (int r = 0; r < 4; ++r) {
        atomicAdd(&a_s2[nb + mb + r], ps[r]);
        atomicAdd(&a_d2[nb + mb + r], pd[r]);
      }
    }
  }
}

// ================= layer-2 gather + bias + log_softmax, 4 nodes/block
__global__ __launch_bounds__(256) void gath2_k(const int* __restrict__ start, const int* __restrict__ deg,
                                               const int* __restrict__ csr_src,
                                               const float* __restrict__ a_s, const float* __restrict__ a_d,
                                               const float* __restrict__ h2, const float* __restrict__ b2,
                                               void* __restrict__ outv, const int* __restrict__ flags) {
  int w = threadIdx.x >> 6, lane = threadIdx.x & 63;
  int n = blockIdx.x * 4 + w;
  int s0 = start[n], cnt = deg[n];
  float ad = a_d[n];
  float acc = 0.f, den = 0.f;
  for (int j = s0; j < s0 + cnt; ++j) {
    int s = csr_src[j];
    float v = a_s[s] + ad;
    v = v > 0.f ? v : NEG * v;
    float e = expf(v);
    den += e;
    if (lane < C2) acc += e * h2[(size_t)s * C2 + lane];
  }
  float raw = (lane < C2) ? acc / (den + 1e-16f) + b2[lane] : -1e30f;
  float m = raw;
  #pragma unroll
  for (int o = 32; o > 0; o >>= 1) m = fmaxf(m, __shfl_down(m, o, 64));
  m = __shfl(m, 0, 64);
  float e2 = (lane < C2) ? expf(raw - m) : 0.f;
  float ssum = e2;
  #pragma unroll
  for (int o = 32; o > 0; o >>= 1) ssum += __shfl_down(ssum, o, 64);
  ssum = __shfl(ssum, 0, 64);
  if (lane < C2) {
    float v = raw - m - logf(ssum);
    if (flags[1]) ((float*)outv)[(size_t)n * C2 + lane] = v;
    else          ((u16*) outv)[(size_t)n * C2 + lane] = f2bf(v);
  }
}

extern "C" void kernel_launch(void* const* d_in, const int* in_sizes, int n_in,
                              void* d_out, int out_size, void* d_ws, size_t ws_size,
                              hipStream_t stream) {
  const void* x   = d_in[0];
  const int*  ei  = (const int*)d_in[1];
  const void* W1  = d_in[2];
  const void* as1 = d_in[3];
  const void* ad1 = d_in[4];
  const void* b1  = d_in[5];
  const void* W2  = d_in[6];
  const void* as2 = d_in[7];
  const void* ad2 = d_in[8];
  const void* b2  = d_in[9];

  char* ws = (char*)d_ws;
  u16*   h1      = (u16*)  (ws);                  // 163,840,000
  float* h2      = (float*)(ws + 163840000);      //   6,720,000
  float* a_s1    = (float*)(ws + 170560000);      //   1,280,000
  float* a_d1    = (float*)(ws + 171840000);      //   1,280,000
  float* a_s2    = (float*)(ws + 173120000);      //     160,000
  float* a_d2    = (float*)(ws + 173280000);      //     160,000
  int*   deg     = (int*)  (ws + 173440000);      //     160,000
  int*   start   = (int*)  (ws + 173600000);      //     160,000
  int*   cur     = (int*)  (ws + 173760000);      //     160,000
  int*   tmp     = (int*)  (ws + 173920000);      //     160,000
  int*   csr_src = (int*)  (ws + 174080000);      //     800,000
  int*   csr_dst = (int*)  (ws + 174880000);      //     800,000
  int*   bsum    = (int*)  (ws + 175680000);      //       1,024
  u16*   w1t     = (u16*)  (ws + 175681024);      //   2,490,368
  u16*   w2t     = (u16*)  (ws + 178171392);      //     262,144
  float* as1c    = (float*)(ws + 178433536);      //       8,192
  float* ad1c    = (float*)(ws + 178441728);      //       8,192
  float* b1c     = (float*)(ws + 178449920);      //       8,192
  float* as2c    = (float*)(ws + 178458112);      //         256
  float* ad2c    = (float*)(ws + 178458368);      //         256
  float* b2c     = (float*)(ws + 178458624);      //         256
  int*   flags   = (int*)  (ws + 178458880);      //         256
  const size_t TOTAL_BASE = 178459136;
  u16*   xb      = (u16*)  (ws + TOTAL_BASE);     //  48,873,472 (path A only)
  const size_t TOTAL_A = TOTAL_BASE + (size_t)MP * KP * 2;  // 227,332,608 (< proven 233.6MB)
  if (ws_size < TOTAL_BASE) return;
  const bool pathA = (ws_size >= TOTAL_A);

  probe_k<<<1, 64, 0, stream>>>((const u32*)x, ei, flags);

  cvt_all_k<<<(F1 + 255) / 256, 256, 0, stream>>>(as1, ad1, b1, as2, ad2, b2,
                                                  as1c, ad1c, b1c, as2c, ad2c, b2c, flags);
  w1t_k<<<dim3(8, KP), 256, 0, stream>>>(W1, w1t, flags);
  w2t_k<<<(64 * F1 + 255) / 256, 256, 0, stream>>>(W2, w2t, flags);

  hipMemsetAsync(deg, 0, NN * sizeof(int), stream);
  hipMemsetAsync(a_s1, 0, (2 * NN * NH1 + 2 * NN) * sizeof(float), stream);
  const int EB = (ETOT + 255) / 256;
  deg_k  <<<EB, 256, 0, stream>>>(ei, deg, flags);
  scan1_k<<<NB, 256, 0, stream>>>(deg, tmp, bsum);
  scan2_k<<<1, 256, 0, stream>>>(bsum);
  scan3_k<<<NB, 256, 0, stream>>>(deg, tmp, bsum, start, cur);
  fill_k <<<EB, 256, 0, stream>>>(ei, cur, csr_src, csr_dst, flags);

  if (pathA) {
    xb4_k<<<MP, 192, 0, stream>>>(x, xb, flags);
    gemm1c_k<<<dim3(8, MP / 256), 512, 0, stream>>>(xb, w1t, h1, as1c, ad1c, a_s1, a_d1);
  } else {
    gemm1m_k<<<dim3(16, 313), 256, 0, stream>>>(x, w1t, h1, flags);
    att1_k<<<NN, 256, 0, stream>>>(h1, as1c, ad1c, a_s1, a_d1);
  }
  gfuse_k<<<NN / 16, 512, 0, stream>>>(start, deg, csr_src, a_s1, a_d1, h1, b1c, w2t,
                                       as2c, ad2c, h2, a_s2, a_d2);

  gath2_k<<<NN / 4, 256, 0, stream>>>(start, deg, csr_src, a_s2, a_d2, h2, b2c, d_out, flags);
}

// Round 15
// 588.988 us; speedup vs baseline: 1.1598x; 1.0498x over previous
//
#include <hip/hip_runtime.h>
#include <hip/hip_bf16.h>

#define NN   40000
#define NE   160000
#define ETOT 200000   // NE + NN self loops
#define FIN  602
#define NH1  8
#define C1   256
#define F1   2048     // NH1*C1
#define C2   42
#define NEG  0.2f
#define NB   157      // ceil(NN/256)
#define KP   608      // FIN padded to mult of 32
#define MP   40192    // NN padded to mult of 256 (157*256)
#define CSS  264      // Cs LDS row stride (u16), padded vs 256 to spread banks

typedef unsigned short u16;
typedef unsigned int   u32;
typedef __bf16 bf16x8 __attribute__((ext_vector_type(8)));
typedef float  f32x4  __attribute__((ext_vector_type(4)));

__device__ __forceinline__ float bfu(u16 v){ return __uint_as_float(((u32)v) << 16); }
__device__ __forceinline__ float bflo(u32 u){ return __uint_as_float(u << 16); }
__device__ __forceinline__ float bfhi(u32 u){ return __uint_as_float(u & 0xffff0000u); }
__device__ __forceinline__ u16 f2bf(float f){
  u32 u = __float_as_uint(f);
  u32 r = (u + 0x7fffu + ((u >> 16) & 1u)) >> 16;   // RNE
  return (u16)r;
}

// async global->LDS, 16B per lane; LDS dest = wave-uniform base + lane*16
__device__ __forceinline__ void gl_lds16(const u16* g, u16* l) {
  __builtin_amdgcn_global_load_lds(
      (const __attribute__((address_space(1))) u32*)(g),
      (__attribute__((address_space(3))) u32*)(l), 16, 0, 0);
}

// ================= dtype probe =================
__global__ void probe_k(const u32* __restrict__ xw, const int* __restrict__ ei,
                        int* __restrict__ flags) {
  if (threadIdx.x == 0) {
    int zc = 0;
    for (int k = 0; k < 64; ++k) zc += (ei[2*k + 1] == 0) ? 1 : 0;
    flags[0] = (zc == 64) ? 1 : 0;
    int inr = 0;
    for (int k = 0; k < 64; ++k) {
      u32 low = xw[k] & 0xffffu;
      int e = (int)((low >> 7) & 0xff);
      inr += (e >= 100 && e <= 140) ? 1 : 0;
    }
    flags[1] = (inr >= 32) ? 0 : 1;
  }
}

// all small f32 canonicalizations in one launch
__global__ void cvt_all_k(const void* __restrict__ as1, const void* __restrict__ ad1,
                          const void* __restrict__ b1,  const void* __restrict__ as2,
                          const void* __restrict__ ad2, const void* __restrict__ b2,
                          float* __restrict__ as1c, float* __restrict__ ad1c,
                          float* __restrict__ b1c,  float* __restrict__ as2c,
                          float* __restrict__ ad2c, float* __restrict__ b2c,
                          const int* __restrict__ flags) {
  int i = blockIdx.x * 256 + threadIdx.x;
  int fm = flags[1];
  if (i < F1) {
    as1c[i] = fm ? ((const float*)as1)[i] : bfu(((const u16*)as1)[i]);
    ad1c[i] = fm ? ((const float*)ad1)[i] : bfu(((const u16*)ad1)[i]);
    b1c[i]  = fm ? ((const float*)b1)[i]  : bfu(((const u16*)b1)[i]);
  }
  if (i < C2) {
    as2c[i] = fm ? ((const float*)as2)[i] : bfu(((const u16*)as2)[i]);
    ad2c[i] = fm ? ((const float*)ad2)[i] : bfu(((const u16*)ad2)[i]);
    b2c[i]  = fm ? ((const float*)b2)[i]  : bfu(((const u16*)b2)[i]);
  }
}

// xb[MP][KP] = x as bf16, zero-padded rows/cols; 4 elems/thread, 192 thr/row
__global__ __launch_bounds__(192) void xb4_k(const void* __restrict__ x, u16* __restrict__ xb,
                                             const int* __restrict__ flags) {
  int t = threadIdx.x;
  if (t >= 152) return;            // 152*4 = 608 = KP
  int row = blockIdx.x;
  int k0 = t * 4;
  ushort4 o = make_ushort4(0, 0, 0, 0);
  if (row < NN) {
    if (k0 + 4 <= FIN) {
      if (flags[1]) {
        const float* xp = (const float*)x + (size_t)row * FIN + k0;  // 8B aligned
        float2 p0 = *(const float2*)(xp);
        float2 p1 = *(const float2*)(xp + 2);
        o.x = f2bf(p0.x); o.y = f2bf(p0.y); o.z = f2bf(p1.x); o.w = f2bf(p1.y);
      } else {
        const u16* xp = (const u16*)x + (size_t)row * FIN + k0;      // 4B aligned
        u32 p0 = *(const u32*)(xp);
        u32 p1 = *(const u32*)(xp + 2);
        o.x = (u16)(p0 & 0xffff); o.y = (u16)(p0 >> 16);
        o.z = (u16)(p1 & 0xffff); o.w = (u16)(p1 >> 16);
      }
    } else {
      u16 e[4] = {0, 0, 0, 0};
      for (int q = 0; q < 4; ++q) {
        int k = k0 + q;
        if (k < FIN)
          e[q] = flags[1] ? f2bf(((const float*)x)[(size_t)row * FIN + k])
                          : ((const u16*)x)[(size_t)row * FIN + k];
      }
      o = make_ushort4(e[0], e[1], e[2], e[3]);
    }
  }
  *(ushort4*)(xb + (size_t)row * KP + k0) = o;   // 8B aligned
}

// W1t[n][k] = W1[k][n], k padded to 608 with zeros. bf16.
__global__ void w1t_k(const void* __restrict__ W1, u16* __restrict__ w1t,
                      const int* __restrict__ flags) {
  int n = blockIdx.x * 256 + threadIdx.x;
  int k = blockIdx.y;
  if (n >= F1) return;
  u16 v = 0;
  if (k < FIN) v = flags[1] ? f2bf(((const float*)W1)[(size_t)k * F1 + n])
                            : ((const u16*)W1)[(size_t)k * F1 + n];
  w1t[(size_t)n * KP + k] = v;
}

// w2t[c][k] = W2[k][c], c padded 42->64 with zeros. bf16.
__global__ void w2t_k(const void* __restrict__ W2, u16* __restrict__ w2t,
                      const int* __restrict__ flags) {
  int i = blockIdx.x * 256 + threadIdx.x;
  if (i >= 64 * F1) return;
  int c = i >> 11, k = i & (F1 - 1);
  u16 v = 0;
  if (c < C2) v = flags[1] ? f2bf(((const float*)W2)[(size_t)k * C2 + c])
                           : ((const u16*)W2)[(size_t)k * C2 + c];
  w2t[i] = v;
}

// ================= CSR build =================
__device__ __forceinline__ void edge_sd(const int* __restrict__ ei, int e, int imode,
                                        int& s, int& d) {
  if (e < NE) {
    if (imode) { s = ei[2*e]; d = ei[2*(NE + e)]; }
    else       { s = ei[e];   d = ei[NE + e];     }
  } else { s = d = e - NE; }
}

__global__ void deg_k(const int* __restrict__ ei, int* __restrict__ deg,
                      const int* __restrict__ flags) {
  int e = blockIdx.x * 256 + threadIdx.x;
  if (e >= ETOT) return;
  int s, d; edge_sd(ei, e, flags[0], s, d);
  atomicAdd(&deg[d], 1);
}

__global__ __launch_bounds__(256) void scan1_k(const int* __restrict__ deg,
                                               int* __restrict__ tmp, int* __restrict__ bsum) {
  __shared__ int s[256];
  int b = blockIdx.x, t = threadIdx.x, i = b * 256 + t;
  int v = (i < NN) ? deg[i] : 0;
  s[t] = v; __syncthreads();
  for (int o = 1; o < 256; o <<= 1) {
    int u = (t >= o) ? s[t - o] : 0;
    __syncthreads(); s[t] += u; __syncthreads();
  }
  if (i < NN) tmp[i] = s[t];
  if (t == 255) bsum[b] = s[255];
}

__global__ __launch_bounds__(256) void scan2_k(int* __restrict__ bsum) {
  __shared__ int s[256];
  int t = threadIdx.x;
  int v = (t < NB) ? bsum[t] : 0;
  s[t] = v; __syncthreads();
  for (int o = 1; o < 256; o <<= 1) {
    int u = (t >= o) ? s[t - o] : 0;
    __syncthreads(); s[t] += u; __syncthreads();
  }
  if (t < NB) bsum[t] = s[t];
}

__global__ void scan3_k(const int* __restrict__ deg, const int* __restrict__ tmp,
                        const int* __restrict__ bsum, int* __restrict__ start, int* __restrict__ cur) {
  int i = blockIdx.x * 256 + threadIdx.x;
  if (i >= NN) return;
  int b = i >> 8;
  int off = b ? bsum[b - 1] : 0;
  int excl = tmp[i] - deg[i] + off;
  start[i] = excl; cur[i] = excl;
}

__global__ void fill_k(const int* __restrict__ ei, int* __restrict__ cur,
                       int* __restrict__ csr_src, int* __restrict__ csr_dst,
                       const int* __restrict__ flags) {
  int e = blockIdx.x * 256 + threadIdx.x;
  if (e >= ETOT) return;
  int s, d; edge_sd(ei, e, flags[0], s, d);
  int pos = atomicAdd(&cur[d], 1);
  csr_src[pos] = s; csr_dst[pos] = d;
}

// ================= GEMM1 path A (R13-exact, measured 273us): 256x256 tile, BK=32,
// 8 waves (2x4), 2-buffer global_load_lds + plain __syncthreads (compiler schedule),
// chunk-XOR swizzle, fused att1 partials, coalesced C-store via LDS round-trip.
__global__ __launch_bounds__(512) void gemm1c_k(const u16* __restrict__ xb,
                                                const u16* __restrict__ w1t,
                                                u16* __restrict__ h1,
                                                const float* __restrict__ as1c,
                                                const float* __restrict__ ad1c,
                                                float* __restrict__ a_s1,
                                                float* __restrict__ a_d1) {
  __shared__ u16 As[2 * 8192];   // [buf][256 rows][32 k] = 32 KB (reused as Cs in epilogue)
  __shared__ u16 Bs[2 * 8192];
  const int t = threadIdx.x;
  const int lane = t & 63, wid = t >> 6;   // 8 waves
  const int wr = wid >> 2, wc = wid & 3;   // 2 x 4 wave grid, wave tile 128x64
  const int m0 = blockIdx.y * 256, n0 = blockIdx.x * 256;
  const int l16 = lane & 15;
  f32x4 acc[8][4];
  #pragma unroll
  for (int i = 0; i < 8; ++i)
    #pragma unroll
    for (int j = 0; j < 4; ++j) acc[i][j] = (f32x4){0.f, 0.f, 0.f, 0.f};

  const int kc = ((t & 3) ^ ((t >> 3) & 3)) * 8;
  const size_t sa0 = (size_t)(m0 + (t >> 2)) * KP + kc;
  const size_t sa1 = sa0 + (size_t)128 * KP;
  const size_t sb0 = (size_t)(n0 + (t >> 2)) * KP + kc;
  const size_t sb1 = sb0 + (size_t)128 * KP;

  const int fsw = ((lane >> 4) ^ ((l16 >> 1) & 3)) << 3;
  const int rdA = (wr * 128 + l16) * 32 + fsw;   // + mi*512
  const int rdB = (wc * 64 + l16) * 32 + fsw;    // + ni*512

#define STAGE(K0, B) do {                                  \
    u16* a_ = As + (B) * 8192 + (wid << 9);                \
    u16* b_ = Bs + (B) * 8192 + (wid << 9);                \
    gl_lds16(xb  + sa0 + (K0), a_);                        \
    gl_lds16(xb  + sa1 + (K0), a_ + 4096);                 \
    gl_lds16(w1t + sb0 + (K0), b_);                        \
    gl_lds16(w1t + sb1 + (K0), b_ + 4096);                 \
  } while (0)

  STAGE(0, 0);
  __syncthreads();
  int cur = 0;
  for (int k0 = 0; k0 < KP; k0 += 32) {
    if (k0 + 32 < KP) STAGE(k0 + 32, cur ^ 1);   // prefetch next K-tile
    const u16* Ab = As + cur * 8192;
    const u16* Bb = Bs + cur * 8192;
    bf16x8 bfr[4];
    #pragma unroll
    for (int ni = 0; ni < 4; ++ni)
      bfr[ni] = *(const bf16x8*)&Bb[rdB + ni * 512];
    #pragma unroll
    for (int mi = 0; mi < 8; ++mi) {
      bf16x8 af = *(const bf16x8*)&Ab[rdA + mi * 512];
      #pragma unroll
      for (int ni = 0; ni < 4; ++ni)
        acc[mi][ni] = __builtin_amdgcn_mfma_f32_16x16x32_bf16(af, bfr[ni], acc[mi][ni], 0, 0, 0);
    }
    __syncthreads();   // next stage landed; cur reads done
    cur ^= 1;
  }
#undef STAGE

  // ---- fused att1: per-row weighted col sums -> shfl reduce -> atomic partials
  const int h0 = n0 >> 8;          // head of this col tile (N-tile == C1)
  const int lr4 = (lane >> 4) * 4;
  #pragma unroll
  for (int mi = 0; mi < 8; ++mi) {
    float ps[4] = {0.f, 0.f, 0.f, 0.f}, pd[4] = {0.f, 0.f, 0.f, 0.f};
    #pragma unroll
    for (int ni = 0; ni < 4; ++ni) {
      int col = n0 + wc * 64 + ni * 16 + l16;
      float wsv = as1c[col], wdv = ad1c[col];
      #pragma unroll
      for (int r = 0; r < 4; ++r) {
        float v = acc[mi][ni][r];
        ps[r] += v * wsv;
        pd[r] += v * wdv;
      }
    }
    #pragma unroll
    for (int o = 1; o < 16; o <<= 1) {
      #pragma unroll
      for (int r = 0; r < 4; ++r) {
        ps[r] += __shfl_xor(ps[r], o, 64);
        pd[r] += __shfl_xor(pd[r], o, 64);
      }
    }
    if (l16 == 0) {
      int rowb = m0 + wr * 128 + mi * 16 + lr4;
      #pragma unroll
      for (int r = 0; r < 4; ++r) {
        int row = rowb + r;
        if (row < NN) {
          atomicAdd(&a_s1[row * NH1 + h0], ps[r]);
          atomicAdd(&a_d1[row * NH1 + h0], pd[r]);
        }
      }
    }
  }

  // ---- C store via LDS (coalesced): 8 passes of 32 rows; Cs reuses As (16.9 KB)
  u16* Cs = As;
  const int rrow = t >> 4;          // 0..31 LDS row
  const int rchk = t & 15;          // 16-u16 (32B) chunk within row
  for (int mi = 0; mi < 8; ++mi) {
    __syncthreads();               // previous pass readback done
    #pragma unroll
    for (int ni = 0; ni < 4; ++ni)
      #pragma unroll
      for (int r = 0; r < 4; ++r)
        Cs[(wr * 16 + lr4 + r) * CSS + wc * 64 + ni * 16 + l16] = f2bf(acc[mi][ni][r]);
    __syncthreads();
    int grow = m0 + (rrow >> 4) * 128 + mi * 16 + (rrow & 15);
    if (grow < NN) {
      const uint4* src = (const uint4*)&Cs[rrow * CSS + rchk * 16];
      uint4 v0 = src[0], v1 = src[1];
      uint4* dst = (uint4*)&h1[(size_t)grow * F1 + n0 + rchk * 16];
      dst[0] = v0; dst[1] = v1;
    }
  }
}

// ================= GEMM1 path B (fallback, reg-staged, dual-dtype) =================
__global__ __launch_bounds__(256) void gemm1m_k(const void* __restrict__ xv,
                                                const u16* __restrict__ w1t,
                                                u16* __restrict__ h1,
                                                const int* __restrict__ flags) {
  __shared__ u16 As[128][40];
  __shared__ u16 Bs[128][40];
  const int fm = flags[1];
  const int t = threadIdx.x;
  const int lane = t & 63, wid = t >> 6;
  const int wr = wid >> 1, wc = wid & 1;
  const int m0 = blockIdx.y * 128, n0 = blockIdx.x * 128;
  const int l16 = lane & 15, lk = (lane >> 4) * 8;
  f32x4 acc[4][4];
  #pragma unroll
  for (int i = 0; i < 4; ++i)
    #pragma unroll
    for (int j = 0; j < 4; ++j) acc[i][j] = (f32x4){0.f, 0.f, 0.f, 0.f};
  const int arow = t >> 2;
  const int akb  = (t & 3) * 8;
  for (int k0 = 0; k0 < KP; k0 += 32) {
    #pragma unroll
    for (int i = 0; i < 2; ++i) {
      int row = arow + i * 64;
      int rg = m0 + row;
      u32 d0 = 0, d1 = 0, d2 = 0, d3 = 0;
      if (rg < NN) {
        if (k0 + 32 <= FIN) {
          if (fm) {
            const float* xp = (const float*)xv + (size_t)rg * FIN + k0 + akb;
            float2 p0 = *(const float2*)(xp);
            float2 p1 = *(const float2*)(xp + 2);
            float2 p2 = *(const float2*)(xp + 4);
            float2 p3 = *(const float2*)(xp + 6);
            d0 = (u32)f2bf(p0.x) | ((u32)f2bf(p0.y) << 16);
            d1 = (u32)f2bf(p1.x) | ((u32)f2bf(p1.y) << 16);
            d2 = (u32)f2bf(p2.x) | ((u32)f2bf(p2.y) << 16);
            d3 = (u32)f2bf(p3.x) | ((u32)f2bf(p3.y) << 16);
          } else {
            const u16* xp = (const u16*)xv + (size_t)rg * FIN + k0 + akb;
            d0 = *(const u32*)(xp);
            d1 = *(const u32*)(xp + 2);
            d2 = *(const u32*)(xp + 4);
            d3 = *(const u32*)(xp + 6);
          }
        } else {
          u16 e[8];
          #pragma unroll
          for (int q = 0; q < 8; ++q) {
            int k = k0 + akb + q;
            e[q] = 0;
            if (k < FIN)
              e[q] = fm ? f2bf(((const float*)xv)[(size_t)rg * FIN + k])
                        : ((const u16*)xv)[(size_t)rg * FIN + k];
          }
          d0 = (u32)e[0] | ((u32)e[1] << 16);
          d1 = (u32)e[2] | ((u32)e[3] << 16);
          d2 = (u32)e[4] | ((u32)e[5] << 16);
          d3 = (u32)e[6] | ((u32)e[7] << 16);
        }
      }
      *(uint4*)&As[row][akb] = make_uint4(d0, d1, d2, d3);
      const u16* wp = w1t + (size_t)(n0 + row) * KP + k0 + akb;
      *(uint4*)&Bs[row][akb] = *(const uint4*)wp;
    }
    __syncthreads();
    bf16x8 bfr[4];
    #pragma unroll
    for (int ni = 0; ni < 4; ++ni)
      bfr[ni] = *(const bf16x8*)&Bs[wc * 64 + ni * 16 + l16][lk];
    #pragma unroll
    for (int mi = 0; mi < 4; ++mi) {
      bf16x8 af = *(const bf16x8*)&As[wr * 64 + mi * 16 + l16][lk];
      #pragma unroll
      for (int ni = 0; ni < 4; ++ni)
        acc[mi][ni] = __builtin_amdgcn_mfma_f32_16x16x32_bf16(af, bfr[ni], acc[mi][ni], 0, 0, 0);
    }
    __syncthreads();
  }
  const int lr4 = (lane >> 4) * 4;
  #pragma unroll
  for (int mi = 0; mi < 4; ++mi) {
    #pragma unroll
    for (int r = 0; r < 4; ++r) {
      int row = m0 + wr * 64 + mi * 16 + lr4 + r;
      if (row < NN) {
        #pragma unroll
        for (int ni = 0; ni < 4; ++ni) {
          int col = n0 + wc * 64 + ni * 16 + l16;
          h1[(size_t)row * F1 + col] = f2bf(acc[mi][ni][r]);
        }
      }
    }
  }
}

// ================= attention scalars (fallback path only)
__global__ __launch_bounds__(256) void att1_k(const u16* __restrict__ h1,
                                              const float* __restrict__ as1c, const float* __restrict__ ad1c,
                                              float* __restrict__ a_s, float* __restrict__ a_d) {
  int n = blockIdx.x, t = threadIdx.x;
  int h = t >> 5, l = t & 31;
  int base = h * C1 + l * 8;
  const u16* hp = h1 + (size_t)n * F1 + base;
  uint4 v = *(const uint4*)hp;
  u32 w[4] = {v.x, v.y, v.z, v.w};
  float ss = 0.f, sd = 0.f;
  #pragma unroll
  for (int p = 0; p < 4; ++p) {
    float e0 = bflo(w[p]), e1 = bfhi(w[p]);
    ss += e0 * as1c[base + 2*p] + e1 * as1c[base + 2*p + 1];
    sd += e0 * ad1c[base + 2*p] + e1 * ad1c[base + 2*p + 1];
  }
  #pragma unroll
  for (int o = 16; o > 0; o >>= 1) {
    ss += __shfl_down(ss, o, 32);
    sd += __shfl_down(sd, o, 32);
  }
  if (l == 0) { a_s[n * NH1 + h] = ss; a_d[n * NH1 + h] = sd; }
}

// per-edge contribution helper for gfuse gather
#define EDGE_ACC(S)                                                   \
  do {                                                                \
    float v_ = a_s1[(S) * NH1 + h] + ad;                              \
    v_ = v_ > 0.f ? v_ : NEG * v_;                                    \
    float e_ = expf(v_);                                              \
    uint4 u_ = *(const uint4*)(h1 + (size_t)(S) * F1 + c0);           \
    den += e_;                                                        \
    a0 += e_ * bflo(u_.x); a1 += e_ * bfhi(u_.x);                     \
    a2 += e_ * bflo(u_.y); a3 += e_ * bfhi(u_.y);                     \
    a4 += e_ * bflo(u_.z); a5 += e_ * bfhi(u_.z);                     \
    a6 += e_ * bflo(u_.w); a7 += e_ * bfhi(u_.w);                     \
  } while (0)

// ================= fused: gather+bias+ReLU -> LDS -> MFMA @ w2t -> h2 + fused att2
__global__ __launch_bounds__(512) void gfuse_k(const int* __restrict__ start, const int* __restrict__ deg,
                                               const int* __restrict__ csr_src,
                                               const float* __restrict__ a_s1, const float* __restrict__ a_d1,
                                               const u16* __restrict__ h1, const float* __restrict__ b1c,
                                               const u16* __restrict__ w2t,
                                               const float* __restrict__ as2c, const float* __restrict__ ad2c,
                                               float* __restrict__ h2,
                                               float* __restrict__ a_s2, float* __restrict__ a_d2) {
  __shared__ u16 rowsL[16 * F1];   // 64 KB
  __shared__ float pb[4][16][16];  // 4 KB K-half partials
  int t = threadIdx.x;
  int nb = blockIdx.x * 16;
  int sub = t & 255, grp = t >> 8;
  int h = sub >> 5;
  int c0 = sub * 8;
  float4 bA = *(const float4*)(b1c + c0);
  float4 bB = *(const float4*)(b1c + c0 + 4);
  for (int ii = 0; ii < 8; ++ii) {
    int i = grp * 8 + ii;
    int n = nb + i;
    int s0 = start[n], jend = s0 + deg[n];
    float ad = a_d1[n * NH1 + h];
    float a0=0.f,a1=0.f,a2=0.f,a3=0.f,a4=0.f,a5=0.f,a6=0.f,a7=0.f,den=0.f;
    int j = s0;
    for (; j + 4 <= jend; j += 4) {     // 4-deep MLP: 12 loads in flight
      int sA = csr_src[j],     sB = csr_src[j + 1];
      int sC = csr_src[j + 2], sD = csr_src[j + 3];
      EDGE_ACC(sA); EDGE_ACC(sB); EDGE_ACC(sC); EDGE_ACC(sD);
    }
    for (; j < jend; ++j) {
      int sA = csr_src[j];
      EDGE_ACC(sA);
    }
    float inv = 1.f / (den + 1e-16f);
    u16 o0 = f2bf(fmaxf(a0 * inv + bA.x, 0.f));
    u16 o1 = f2bf(fmaxf(a1 * inv + bA.y, 0.f));
    u16 o2 = f2bf(fmaxf(a2 * inv + bA.z, 0.f));
    u16 o3 = f2bf(fmaxf(a3 * inv + bA.w, 0.f));
    u16 o4 = f2bf(fmaxf(a4 * inv + bB.x, 0.f));
    u16 o5 = f2bf(fmaxf(a5 * inv + bB.y, 0.f));
    u16 o6 = f2bf(fmaxf(a6 * inv + bB.z, 0.f));
    u16 o7 = f2bf(fmaxf(a7 * inv + bB.w, 0.f));
    uint4 pk;
    pk.x = (u32)o0 | ((u32)o1 << 16);
    pk.y = (u32)o2 | ((u32)o3 << 16);
    pk.z = (u32)o4 | ((u32)o5 << 16);
    pk.w = (u32)o6 | ((u32)o7 << 16);
    int sw = (i & 7) << 3;
    *(uint4*)&rowsL[i * F1 + (c0 ^ sw)] = pk;
  }
  __syncthreads();
  // phase B: C[16 nodes][64 cols] = rowsL @ w2t^T; wave = (col-group g, K-half kh)
  int lane = t & 63, wid = t >> 6;       // 8 waves
  int g = wid & 3, kh = wid >> 2;
  int l16 = lane & 15, lk = (lane >> 4) * 8;
  const u16* wt = w2t + (size_t)(g * 16 + l16) * F1;
  int sw = (l16 & 7) << 3;
  f32x4 acc2 = (f32x4){0.f, 0.f, 0.f, 0.f};
  const int kbase = kh * (F1 / 2);
  for (int k0 = 0; k0 < F1 / 2; k0 += 32) {
    int kk = kbase + k0 + lk;
    bf16x8 af = *(const bf16x8*)&rowsL[l16 * F1 + (kk ^ sw)];
    bf16x8 bf = *(const bf16x8*)(wt + kk);
    acc2 = __builtin_amdgcn_mfma_f32_16x16x32_bf16(af, bf, acc2, 0, 0, 0);
  }
  int mb = (lane >> 4) * 4;
  if (kh == 1) {
    #pragma unroll
    for (int r = 0; r < 4; ++r) pb[g][mb + r][l16] = acc2[r];
  }
  __syncthreads();
  if (kh == 0) {
    int col = g * 16 + l16;
    float vals[4];
    #pragma unroll
    for (int r = 0; r < 4; ++r) vals[r] = acc2[r] + pb[g][mb + r][l16];
    if (col < C2) {
      #pragma unroll
      for (int r = 0; r < 4; ++r)
        h2[(size_t)(nb + mb + r) * C2 + col] = vals[r];
    }
    // fused att2: per-row dot with as2/ad2, reduce over 16-lane col group
    float as2v = (col < C2) ? as2c[col] : 0.f;
    float ad2v = (col < C2) ? ad2c[col] : 0.f;
    float ps[4], pd[4];
    #pragma unroll
    for (int r = 0; r < 4; ++r) { ps[r] = vals[r] * as2v; pd[r] = vals[r] * ad2v; }
    #pragma unroll
    for (int o = 1; o < 16; o <<= 1) {
      #pragma unroll
      for (int r = 0; r < 4; ++r) {
        ps[r] += __shfl_xor(ps[r], o, 64);
        pd[r] += __shfl_xor(pd[r], o, 64);
      }
    }
    if (l16 == 0 && g < 3) {   // g==3 cols are all >= C2 (zero contribution)
      #pragma unroll
      for (int r = 0; r < 4; ++r) {
        atomicAdd(&a_s2[nb + mb + r], ps[r]);
        atomicAdd(&a_d2[nb + mb + r], pd[r]);
      }
    }
  }
}

// ================= layer-2 gather + bias + log_softmax, 4 nodes/block
__global__ __launch_bounds__(256) void gath2_k(const int* __restrict__ start, const int* __restrict__ deg,
                                               const int* __restrict__ csr_src,
                                               const float* __restrict__ a_s, const float* __restrict__ a_d,
                                               const float* __restrict__ h2, const float* __restrict__ b2,
                                               void* __restrict__ outv, const int* __restrict__ flags) {
  int w = threadIdx.x >> 6, lane = threadIdx.x & 63;
  int n = blockIdx.x * 4 + w;
  int s0 = start[n], cnt = deg[n];
  float ad = a_d[n];
  float acc = 0.f, den = 0.f;
  for (int j = s0; j < s0 + cnt; ++j) {
    int s = csr_src[j];
    float v = a_s[s] + ad;
    v = v > 0.f ? v : NEG * v;
    float e = expf(v);
    den += e;
    if (lane < C2) acc += e * h2[(size_t)s * C2 + lane];
  }
  float raw = (lane < C2) ? acc / (den + 1e-16f) + b2[lane] : -1e30f;
  float m = raw;
  #pragma unroll
  for (int o = 32; o > 0; o >>= 1) m = fmaxf(m, __shfl_down(m, o, 64));
  m = __shfl(m, 0, 64);
  float e2 = (lane < C2) ? expf(raw - m) : 0.f;
  float ssum = e2;
  #pragma unroll
  for (int o = 32; o > 0; o >>= 1) ssum += __shfl_down(ssum, o, 64);
  ssum = __shfl(ssum, 0, 64);
  if (lane < C2) {
    float v = raw - m - logf(ssum);
    if (flags[1]) ((float*)outv)[(size_t)n * C2 + lane] = v;
    else          ((u16*) outv)[(size_t)n * C2 + lane] = f2bf(v);
  }
}

extern "C" void kernel_launch(void* const* d_in, const int* in_sizes, int n_in,
                              void* d_out, int out_size, void* d_ws, size_t ws_size,
                              hipStream_t stream) {
  const void* x   = d_in[0];
  const int*  ei  = (const int*)d_in[1];
  const void* W1  = d_in[2];
  const void* as1 = d_in[3];
  const void* ad1 = d_in[4];
  const void* b1  = d_in[5];
  const void* W2  = d_in[6];
  const void* as2 = d_in[7];
  const void* ad2 = d_in[8];
  const void* b2  = d_in[9];

  char* ws = (char*)d_ws;
  u16*   h1      = (u16*)  (ws);                  // 163,840,000
  float* h2      = (float*)(ws + 163840000);      //   6,720,000
  float* a_s1    = (float*)(ws + 170560000);      //   1,280,000
  float* a_d1    = (float*)(ws + 171840000);      //   1,280,000
  float* a_s2    = (float*)(ws + 173120000);      //     160,000
  float* a_d2    = (float*)(ws + 173280000);      //     160,000
  int*   deg     = (int*)  (ws + 173440000);      //     160,000
  int*   start   = (int*)  (ws + 173600000);      //     160,000
  int*   cur     = (int*)  (ws + 173760000);      //     160,000
  int*   tmp     = (int*)  (ws + 173920000);      //     160,000
  int*   csr_src = (int*)  (ws + 174080000);      //     800,000
  int*   csr_dst = (int*)  (ws + 174880000);      //     800,000
  int*   bsum    = (int*)  (ws + 175680000);      //       1,024
  u16*   w1t     = (u16*)  (ws + 175681024);      //   2,490,368
  u16*   w2t     = (u16*)  (ws + 178171392);      //     262,144
  float* as1c    = (float*)(ws + 178433536);      //       8,192
  float* ad1c    = (float*)(ws + 178441728);      //       8,192
  float* b1c     = (float*)(ws + 178449920);      //       8,192
  float* as2c    = (float*)(ws + 178458112);      //         256
  float* ad2c    = (float*)(ws + 178458368);      //         256
  float* b2c     = (float*)(ws + 178458624);      //         256
  int*   flags   = (int*)  (ws + 178458880);      //         256
  const size_t TOTAL_BASE = 178459136;
  u16*   xb      = (u16*)  (ws + TOTAL_BASE);     //  48,873,472 (path A only)
  const size_t TOTAL_A = TOTAL_BASE + (size_t)MP * KP * 2;  // 227,332,608 (< proven 233.6MB)
  if (ws_size < TOTAL_BASE) return;
  const bool pathA = (ws_size >= TOTAL_A);

  probe_k<<<1, 64, 0, stream>>>((const u32*)x, ei, flags);

  cvt_all_k<<<(F1 + 255) / 256, 256, 0, stream>>>(as1, ad1, b1, as2, ad2, b2,
                                                  as1c, ad1c, b1c, as2c, ad2c, b2c, flags);
  w1t_k<<<dim3(8, KP), 256, 0, stream>>>(W1, w1t, flags);
  w2t_k<<<(64 * F1 + 255) / 256, 256, 0, stream>>>(W2, w2t, flags);

  hipMemsetAsync(deg, 0, NN * sizeof(int), stream);
  hipMemsetAsync(a_s1, 0, (2 * NN * NH1 + 2 * NN) * sizeof(float), stream);
  const int EB = (ETOT + 255) / 256;
  deg_k  <<<EB, 256, 0, stream>>>(ei, deg, flags);
  scan1_k<<<NB, 256, 0, stream>>>(deg, tmp, bsum);
  scan2_k<<<1, 256, 0, stream>>>(bsum);
  scan3_k<<<NB, 256, 0, stream>>>(deg, tmp, bsum, start, cur);
  fill_k <<<EB, 256, 0, stream>>>(ei, cur, csr_src, csr_dst, flags);

  if (pathA) {
    xb4_k<<<MP, 192, 0, stream>>>(x, xb, flags);
    gemm1c_k<<<dim3(8, MP / 256), 512, 0, stream>>>(xb, w1t, h1, as1c, ad1c, a_s1, a_d1);
  } else {
    gemm1m_k<<<dim3(16, 313), 256, 0, stream>>>(x, w1t, h1, flags);
    att1_k<<<NN, 256, 0, stream>>>(h1, as1c, ad1c, a_s1, a_d1);
  }
  gfuse_k<<<NN / 16, 512, 0, stream>>>(start, deg, csr_src, a_s1, a_d1, h1, b1c, w2t,
                                       as2c, ad2c, h2, a_s2, a_d2);

  gath2_k<<<NN / 4, 256, 0, stream>>>(start, deg, csr_src, a_s2, a_d2, h2, b2c, d_out, flags);
}

// Round 16
// 582.705 us; speedup vs baseline: 1.1724x; 1.0108x over previous
//
#include <hip/hip_runtime.h>
#include <hip/hip_bf16.h>

#define NN   40000
#define NE   160000
#define ETOT 200000   // NE + NN self loops
#define FIN  602
#define NH1  8
#define C1   256
#define F1   2048     // NH1*C1
#define C2   42
#define NEG  0.2f
#define NB   157      // ceil(NN/256)
#define KP   608      // FIN padded to mult of 32
#define MP   40192    // NN padded to mult of 256 (157*256)
#define CSS  264      // Cs LDS row stride (u16), padded vs 256 to spread banks

typedef unsigned short u16;
typedef unsigned int   u32;
typedef __bf16 bf16x8 __attribute__((ext_vector_type(8)));
typedef float  f32x4  __attribute__((ext_vector_type(4)));

__device__ __forceinline__ float bfu(u16 v){ return __uint_as_float(((u32)v) << 16); }
__device__ __forceinline__ float bflo(u32 u){ return __uint_as_float(u << 16); }
__device__ __forceinline__ float bfhi(u32 u){ return __uint_as_float(u & 0xffff0000u); }
__device__ __forceinline__ u16 f2bf(float f){
  u32 u = __float_as_uint(f);
  u32 r = (u + 0x7fffu + ((u >> 16) & 1u)) >> 16;   // RNE
  return (u16)r;
}

// async global->LDS, 16B per lane; LDS dest = wave-uniform base + lane*16
__device__ __forceinline__ void gl_lds16(const u16* g, u16* l) {
  __builtin_amdgcn_global_load_lds(
      (const __attribute__((address_space(1))) u32*)(g),
      (__attribute__((address_space(3))) u32*)(l), 16, 0, 0);
}

// ================= dtype probe =================
__global__ void probe_k(const u32* __restrict__ xw, const int* __restrict__ ei,
                        int* __restrict__ flags) {
  if (threadIdx.x == 0) {
    int zc = 0;
    for (int k = 0; k < 64; ++k) zc += (ei[2*k + 1] == 0) ? 1 : 0;
    flags[0] = (zc == 64) ? 1 : 0;
    int inr = 0;
    for (int k = 0; k < 64; ++k) {
      u32 low = xw[k] & 0xffffu;
      int e = (int)((low >> 7) & 0xff);
      inr += (e >= 100 && e <= 140) ? 1 : 0;
    }
    flags[1] = (inr >= 32) ? 0 : 1;
  }
}

// combined: small f32 canonicalizations (blocks 0..7) + w2t transpose-pad (blocks 8..519)
__global__ void prep_k(const void* __restrict__ as1, const void* __restrict__ ad1,
                       const void* __restrict__ b1,  const void* __restrict__ as2,
                       const void* __restrict__ ad2, const void* __restrict__ b2,
                       const void* __restrict__ W2,
                       float* __restrict__ as1c, float* __restrict__ ad1c,
                       float* __restrict__ b1c,  float* __restrict__ as2c,
                       float* __restrict__ ad2c, float* __restrict__ b2c,
                       u16* __restrict__ w2t,
                       const int* __restrict__ flags) {
  int b = blockIdx.x;
  int fm = flags[1];
  if (b < 8) {
    int i = b * 256 + threadIdx.x;
    if (i < F1) {
      as1c[i] = fm ? ((const float*)as1)[i] : bfu(((const u16*)as1)[i]);
      ad1c[i] = fm ? ((const float*)ad1)[i] : bfu(((const u16*)ad1)[i]);
      b1c[i]  = fm ? ((const float*)b1)[i]  : bfu(((const u16*)b1)[i]);
    }
    if (i < C2) {
      as2c[i] = fm ? ((const float*)as2)[i] : bfu(((const u16*)as2)[i]);
      ad2c[i] = fm ? ((const float*)ad2)[i] : bfu(((const u16*)ad2)[i]);
      b2c[i]  = fm ? ((const float*)b2)[i]  : bfu(((const u16*)b2)[i]);
    }
  } else {
    int i = (b - 8) * 256 + threadIdx.x;   // over 64*F1 = 131072
    int c = i >> 11, k = i & (F1 - 1);
    u16 v = 0;
    if (c < C2) v = fm ? f2bf(((const float*)W2)[(size_t)k * C2 + c])
                       : ((const u16*)W2)[(size_t)k * C2 + c];
    w2t[i] = v;
  }
}

// xb[MP][KP] = x as bf16, zero-padded rows/cols; 4 elems/thread, 192 thr/row
__global__ __launch_bounds__(192) void xb4_k(const void* __restrict__ x, u16* __restrict__ xb,
                                             const int* __restrict__ flags) {
  int t = threadIdx.x;
  if (t >= 152) return;            // 152*4 = 608 = KP
  int row = blockIdx.x;
  int k0 = t * 4;
  ushort4 o = make_ushort4(0, 0, 0, 0);
  if (row < NN) {
    if (k0 + 4 <= FIN) {
      if (flags[1]) {
        const float* xp = (const float*)x + (size_t)row * FIN + k0;  // 8B aligned
        float2 p0 = *(const float2*)(xp);
        float2 p1 = *(const float2*)(xp + 2);
        o.x = f2bf(p0.x); o.y = f2bf(p0.y); o.z = f2bf(p1.x); o.w = f2bf(p1.y);
      } else {
        const u16* xp = (const u16*)x + (size_t)row * FIN + k0;      // 4B aligned
        u32 p0 = *(const u32*)(xp);
        u32 p1 = *(const u32*)(xp + 2);
        o.x = (u16)(p0 & 0xffff); o.y = (u16)(p0 >> 16);
        o.z = (u16)(p1 & 0xffff); o.w = (u16)(p1 >> 16);
      }
    } else {
      u16 e[4] = {0, 0, 0, 0};
      for (int q = 0; q < 4; ++q) {
        int k = k0 + q;
        if (k < FIN)
          e[q] = flags[1] ? f2bf(((const float*)x)[(size_t)row * FIN + k])
                          : ((const u16*)x)[(size_t)row * FIN + k];
      }
      o = make_ushort4(e[0], e[1], e[2], e[3]);
    }
  }
  *(ushort4*)(xb + (size_t)row * KP + k0) = o;   // 8B aligned
}

// W1t[n][k] = W1[k][n] via LDS tile, both sides coalesced. Tile 64n x 32k.
__global__ __launch_bounds__(256) void w1tt_k(const void* __restrict__ W1, u16* __restrict__ w1t,
                                              const int* __restrict__ flags) {
  __shared__ u16 tile[64][40];     // [nn][kk], pad 32->40
  int n0 = blockIdx.x * 64;        // 32 blocks
  int k0 = blockIdx.y * 32;        // 19 blocks
  int t = threadIdx.x;
  int fm = flags[1];
  #pragma unroll
  for (int i = 0; i < 8; ++i) {
    int idx = t + i * 256;         // 2048 elems
    int kk = idx >> 6, nn = idx & 63;
    int k = k0 + kk;
    u16 v = 0;
    if (k < FIN)
      v = fm ? f2bf(((const float*)W1)[(size_t)k * F1 + n0 + nn])
             : ((const u16*)W1)[(size_t)k * F1 + n0 + nn];
    tile[nn][kk] = v;
  }
  __syncthreads();
  int nn = t >> 2, kc = (t & 3) * 8;   // 64 rows x 4 chunks of 8
  uint4 v = *(const uint4*)&tile[nn][kc];      // 16B, aligned (row 80B, kc mult 16B)
  *(uint4*)(w1t + (size_t)(n0 + nn) * KP + k0 + kc) = v;
}

// ================= CSR build =================
__device__ __forceinline__ void edge_sd(const int* __restrict__ ei, int e, int imode,
                                        int& s, int& d) {
  if (e < NE) {
    if (imode) { s = ei[2*e]; d = ei[2*(NE + e)]; }
    else       { s = ei[e];   d = ei[NE + e];     }
  } else { s = d = e - NE; }
}

__global__ void deg_k(const int* __restrict__ ei, int* __restrict__ deg,
                      const int* __restrict__ flags) {
  int e = blockIdx.x * 256 + threadIdx.x;
  if (e >= ETOT) return;
  int s, d; edge_sd(ei, e, flags[0], s, d);
  atomicAdd(&deg[d], 1);
}

__global__ __launch_bounds__(256) void scan1_k(const int* __restrict__ deg,
                                               int* __restrict__ tmp, int* __restrict__ bsum) {
  __shared__ int s[256];
  int b = blockIdx.x, t = threadIdx.x, i = b * 256 + t;
  int v = (i < NN) ? deg[i] : 0;
  s[t] = v; __syncthreads();
  for (int o = 1; o < 256; o <<= 1) {
    int u = (t >= o) ? s[t - o] : 0;
    __syncthreads(); s[t] += u; __syncthreads();
  }
  if (i < NN) tmp[i] = s[t];
  if (t == 255) bsum[b] = s[255];
}

// scan3 with scan2 folded in: block bx sums bsum[0..bx-1] locally
__global__ __launch_bounds__(256) void scan3_k(const int* __restrict__ deg, const int* __restrict__ tmp,
                                               const int* __restrict__ bsum,
                                               int* __restrict__ start, int* __restrict__ cur) {
  __shared__ int s[256];
  int bx = blockIdx.x, t = threadIdx.x;
  s[t] = (t < NB && t < bx) ? bsum[t] : 0;
  __syncthreads();
  #pragma unroll
  for (int o = 128; o > 0; o >>= 1) {
    if (t < o) s[t] += s[t + o];
    __syncthreads();
  }
  int off = s[0];
  int i = bx * 256 + t;
  if (i < NN) {
    int excl = tmp[i] - deg[i] + off;
    start[i] = excl; cur[i] = excl;
  }
}

__global__ void fill_k(const int* __restrict__ ei, int* __restrict__ cur,
                       int* __restrict__ csr_src, int* __restrict__ csr_dst,
                       const int* __restrict__ flags) {
  int e = blockIdx.x * 256 + threadIdx.x;
  if (e >= ETOT) return;
  int s, d; edge_sd(ei, e, flags[0], s, d);
  int pos = atomicAdd(&cur[d], 1);
  csr_src[pos] = s; csr_dst[pos] = d;
}

// ================= GEMM1 path A (R13-exact, measured ~272us): 256x256 tile, BK=32,
// 8 waves (2x4), 2-buffer global_load_lds + plain __syncthreads (compiler schedule),
// chunk-XOR swizzle, fused att1 partials, coalesced C-store via LDS round-trip.
__global__ __launch_bounds__(512) void gemm1c_k(const u16* __restrict__ xb,
                                                const u16* __restrict__ w1t,
                                                u16* __restrict__ h1,
                                                const float* __restrict__ as1c,
                                                const float* __restrict__ ad1c,
                                                float* __restrict__ a_s1,
                                                float* __restrict__ a_d1) {
  __shared__ u16 As[2 * 8192];   // [buf][256 rows][32 k] = 32 KB (reused as Cs in epilogue)
  __shared__ u16 Bs[2 * 8192];
  const int t = threadIdx.x;
  const int lane = t & 63, wid = t >> 6;   // 8 waves
  const int wr = wid >> 2, wc = wid & 3;   // 2 x 4 wave grid, wave tile 128x64
  const int m0 = blockIdx.y * 256, n0 = blockIdx.x * 256;
  const int l16 = lane & 15;
  f32x4 acc[8][4];
  #pragma unroll
  for (int i = 0; i < 8; ++i)
    #pragma unroll
    for (int j = 0; j < 4; ++j) acc[i][j] = (f32x4){0.f, 0.f, 0.f, 0.f};

  const int kc = ((t & 3) ^ ((t >> 3) & 3)) * 8;
  const size_t sa0 = (size_t)(m0 + (t >> 2)) * KP + kc;
  const size_t sa1 = sa0 + (size_t)128 * KP;
  const size_t sb0 = (size_t)(n0 + (t >> 2)) * KP + kc;
  const size_t sb1 = sb0 + (size_t)128 * KP;

  const int fsw = ((lane >> 4) ^ ((l16 >> 1) & 3)) << 3;
  const int rdA = (wr * 128 + l16) * 32 + fsw;   // + mi*512
  const int rdB = (wc * 64 + l16) * 32 + fsw;    // + ni*512

#define STAGE(K0, B) do {                                  \
    u16* a_ = As + (B) * 8192 + (wid << 9);                \
    u16* b_ = Bs + (B) * 8192 + (wid << 9);                \
    gl_lds16(xb  + sa0 + (K0), a_);                        \
    gl_lds16(xb  + sa1 + (K0), a_ + 4096);                 \
    gl_lds16(w1t + sb0 + (K0), b_);                        \
    gl_lds16(w1t + sb1 + (K0), b_ + 4096);                 \
  } while (0)

  STAGE(0, 0);
  __syncthreads();
  int cur = 0;
  for (int k0 = 0; k0 < KP; k0 += 32) {
    if (k0 + 32 < KP) STAGE(k0 + 32, cur ^ 1);   // prefetch next K-tile
    const u16* Ab = As + cur * 8192;
    const u16* Bb = Bs + cur * 8192;
    bf16x8 bfr[4];
    #pragma unroll
    for (int ni = 0; ni < 4; ++ni)
      bfr[ni] = *(const bf16x8*)&Bb[rdB + ni * 512];
    #pragma unroll
    for (int mi = 0; mi < 8; ++mi) {
      bf16x8 af = *(const bf16x8*)&Ab[rdA + mi * 512];
      #pragma unroll
      for (int ni = 0; ni < 4; ++ni)
        acc[mi][ni] = __builtin_amdgcn_mfma_f32_16x16x32_bf16(af, bfr[ni], acc[mi][ni], 0, 0, 0);
    }
    __syncthreads();   // next stage landed; cur reads done
    cur ^= 1;
  }
#undef STAGE

  // ---- fused att1: per-row weighted col sums -> shfl reduce -> atomic partials
  const int h0 = n0 >> 8;          // head of this col tile (N-tile == C1)
  const int lr4 = (lane >> 4) * 4;
  #pragma unroll
  for (int mi = 0; mi < 8; ++mi) {
    float ps[4] = {0.f, 0.f, 0.f, 0.f}, pd[4] = {0.f, 0.f, 0.f, 0.f};
    #pragma unroll
    for (int ni = 0; ni < 4; ++ni) {
      int col = n0 + wc * 64 + ni * 16 + l16;
      float wsv = as1c[col], wdv = ad1c[col];
      #pragma unroll
      for (int r = 0; r < 4; ++r) {
        float v = acc[mi][ni][r];
        ps[r] += v * wsv;
        pd[r] += v * wdv;
      }
    }
    #pragma unroll
    for (int o = 1; o < 16; o <<= 1) {
      #pragma unroll
      for (int r = 0; r < 4; ++r) {
        ps[r] += __shfl_xor(ps[r], o, 64);
        pd[r] += __shfl_xor(pd[r], o, 64);
      }
    }
    if (l16 == 0) {
      int rowb = m0 + wr * 128 + mi * 16 + lr4;
      #pragma unroll
      for (int r = 0; r < 4; ++r) {
        int row = rowb + r;
        if (row < NN) {
          atomicAdd(&a_s1[row * NH1 + h0], ps[r]);
          atomicAdd(&a_d1[row * NH1 + h0], pd[r]);
        }
      }
    }
  }

  // ---- C store via LDS (coalesced): 8 passes of 32 rows; Cs reuses As (16.9 KB)
  u16* Cs = As;
  const int rrow = t >> 4;          // 0..31 LDS row
  const int rchk = t & 15;          // 16-u16 (32B) chunk within row
  for (int mi = 0; mi < 8; ++mi) {
    __syncthreads();               // previous pass readback done
    #pragma unroll
    for (int ni = 0; ni < 4; ++ni)
      #pragma unroll
      for (int r = 0; r < 4; ++r)
        Cs[(wr * 16 + lr4 + r) * CSS + wc * 64 + ni * 16 + l16] = f2bf(acc[mi][ni][r]);
    __syncthreads();
    int grow = m0 + (rrow >> 4) * 128 + mi * 16 + (rrow & 15);
    if (grow < NN) {
      const uint4* src = (const uint4*)&Cs[rrow * CSS + rchk * 16];
      uint4 v0 = src[0], v1 = src[1];
      uint4* dst = (uint4*)&h1[(size_t)grow * F1 + n0 + rchk * 16];
      dst[0] = v0; dst[1] = v1;
    }
  }
}

// ================= GEMM1 path B (fallback, reg-staged, dual-dtype) =================
__global__ __launch_bounds__(256) void gemm1m_k(const void* __restrict__ xv,
                                                const u16* __restrict__ w1t,
                                                u16* __restrict__ h1,
                                                const int* __restrict__ flags) {
  __shared__ u16 As[128][40];
  __shared__ u16 Bs[128][40];
  const int fm = flags[1];
  const int t = threadIdx.x;
  const int lane = t & 63, wid = t >> 6;
  const int wr = wid >> 1, wc = wid & 1;
  const int m0 = blockIdx.y * 128, n0 = blockIdx.x * 128;
  const int l16 = lane & 15, lk = (lane >> 4) * 8;
  f32x4 acc[4][4];
  #pragma unroll
  for (int i = 0; i < 4; ++i)
    #pragma unroll
    for (int j = 0; j < 4; ++j) acc[i][j] = (f32x4){0.f, 0.f, 0.f, 0.f};
  const int arow = t >> 2;
  const int akb  = (t & 3) * 8;
  for (int k0 = 0; k0 < KP; k0 += 32) {
    #pragma unroll
    for (int i = 0; i < 2; ++i) {
      int row = arow + i * 64;
      int rg = m0 + row;
      u32 d0 = 0, d1 = 0, d2 = 0, d3 = 0;
      if (rg < NN) {
        if (k0 + 32 <= FIN) {
          if (fm) {
            const float* xp = (const float*)xv + (size_t)rg * FIN + k0 + akb;
            float2 p0 = *(const float2*)(xp);
            float2 p1 = *(const float2*)(xp + 2);
            float2 p2 = *(const float2*)(xp + 4);
            float2 p3 = *(const float2*)(xp + 6);
            d0 = (u32)f2bf(p0.x) | ((u32)f2bf(p0.y) << 16);
            d1 = (u32)f2bf(p1.x) | ((u32)f2bf(p1.y) << 16);
            d2 = (u32)f2bf(p2.x) | ((u32)f2bf(p2.y) << 16);
            d3 = (u32)f2bf(p3.x) | ((u32)f2bf(p3.y) << 16);
          } else {
            const u16* xp = (const u16*)xv + (size_t)rg * FIN + k0 + akb;
            d0 = *(const u32*)(xp);
            d1 = *(const u32*)(xp + 2);
            d2 = *(const u32*)(xp + 4);
            d3 = *(const u32*)(xp + 6);
          }
        } else {
          u16 e[8];
          #pragma unroll
          for (int q = 0; q < 8; ++q) {
            int k = k0 + akb + q;
            e[q] = 0;
            if (k < FIN)
              e[q] = fm ? f2bf(((const float*)xv)[(size_t)rg * FIN + k])
                        : ((const u16*)xv)[(size_t)rg * FIN + k];
          }
          d0 = (u32)e[0] | ((u32)e[1] << 16);
          d1 = (u32)e[2] | ((u32)e[3] << 16);
          d2 = (u32)e[4] | ((u32)e[5] << 16);
          d3 = (u32)e[6] | ((u32)e[7] << 16);
        }
      }
      *(uint4*)&As[row][akb] = make_uint4(d0, d1, d2, d3);
      const u16* wp = w1t + (size_t)(n0 + row) * KP + k0 + akb;
      *(uint4*)&Bs[row][akb] = *(const uint4*)wp;
    }
    __syncthreads();
    bf16x8 bfr[4];
    #pragma unroll
    for (int ni = 0; ni < 4; ++ni)
      bfr[ni] = *(const bf16x8*)&Bs[wc * 64 + ni * 16 + l16][lk];
    #pragma unroll
    for (int mi = 0; mi < 4; ++mi) {
      bf16x8 af = *(const bf16x8*)&As[wr * 64 + mi * 16 + l16][lk];
      #pragma unroll
      for (int ni = 0; ni < 4; ++ni)
        acc[mi][ni] = __builtin_amdgcn_mfma_f32_16x16x32_bf16(af, bfr[ni], acc[mi][ni], 0, 0, 0);
    }
    __syncthreads();
  }
  const int lr4 = (lane >> 4) * 4;
  #pragma unroll
  for (int mi = 0; mi < 4; ++mi) {
    #pragma unroll
    for (int r = 0; r < 4; ++r) {
      int row = m0 + wr * 64 + mi * 16 + lr4 + r;
      if (row < NN) {
        #pragma unroll
        for (int ni = 0; ni < 4; ++ni) {
          int col = n0 + wc * 64 + ni * 16 + l16;
          h1[(size_t)row * F1 + col] = f2bf(acc[mi][ni][r]);
        }
      }
    }
  }
}

// ================= attention scalars (fallback path only)
__global__ __launch_bounds__(256) void att1_k(const u16* __restrict__ h1,
                                              const float* __restrict__ as1c, const float* __restrict__ ad1c,
                                              float* __restrict__ a_s, float* __restrict__ a_d) {
  int n = blockIdx.x, t = threadIdx.x;
  int h = t >> 5, l = t & 31;
  int base = h * C1 + l * 8;
  const u16* hp = h1 + (size_t)n * F1 + base;
  uint4 v = *(const uint4*)hp;
  u32 w[4] = {v.x, v.y, v.z, v.w};
  float ss = 0.f, sd = 0.f;
  #pragma unroll
  for (int p = 0; p < 4; ++p) {
    float e0 = bflo(w[p]), e1 = bfhi(w[p]);
    ss += e0 * as1c[base + 2*p] + e1 * as1c[base + 2*p + 1];
    sd += e0 * ad1c[base + 2*p] + e1 * ad1c[base + 2*p + 1];
  }
  #pragma unroll
  for (int o = 16; o > 0; o >>= 1) {
    ss += __shfl_down(ss, o, 32);
    sd += __shfl_down(sd, o, 32);
  }
  if (l == 0) { a_s[n * NH1 + h] = ss; a_d[n * NH1 + h] = sd; }
}

// per-edge contribution helper for gfuse gather
#define EDGE_ACC(S)                                                   \
  do {                                                                \
    float v_ = a_s1[(S) * NH1 + h] + ad;                              \
    v_ = v_ > 0.f ? v_ : NEG * v_;                                    \
    float e_ = expf(v_);                                              \
    uint4 u_ = *(const uint4*)(h1 + (size_t)(S) * F1 + c0);           \
    den += e_;                                                        \
    a0 += e_ * bflo(u_.x); a1 += e_ * bfhi(u_.x);                     \
    a2 += e_ * bflo(u_.y); a3 += e_ * bfhi(u_.y);                     \
    a4 += e_ * bflo(u_.z); a5 += e_ * bfhi(u_.z);                     \
    a6 += e_ * bflo(u_.w); a7 += e_ * bfhi(u_.w);                     \
  } while (0)

// ================= fused: gather+bias+ReLU -> LDS -> MFMA @ w2t -> h2 + fused att2
__global__ __launch_bounds__(512) void gfuse_k(const int* __restrict__ start, const int* __restrict__ deg,
                                               const int* __restrict__ csr_src,
                                               const float* __restrict__ a_s1, const float* __restrict__ a_d1,
                                               const u16* __restrict__ h1, const float* __restrict__ b1c,
                                               const u16* __restrict__ w2t,
                                               const float* __restrict__ as2c, const float* __restrict__ ad2c,
                                               float* __restrict__ h2,
                                               float* __restrict__ a_s2, float* __restrict__ a_d2) {
  __shared__ u16 rowsL[16 * F1];   // 64 KB
  __shared__ float pb[4][16][16];  // 4 KB K-half partials
  int t = threadIdx.x;
  int nb = blockIdx.x * 16;
  int sub = t & 255, grp = t >> 8;
  int h = sub >> 5;
  int c0 = sub * 8;
  float4 bA = *(const float4*)(b1c + c0);
  float4 bB = *(const float4*)(b1c + c0 + 4);
  for (int ii = 0; ii < 8; ++ii) {
    int i = grp * 8 + ii;
    int n = nb + i;
    int s0 = start[n], jend = s0 + deg[n];
    float ad = a_d1[n * NH1 + h];
    float a0=0.f,a1=0.f,a2=0.f,a3=0.f,a4=0.f,a5=0.f,a6=0.f,a7=0.f,den=0.f;
    int j = s0;
    for (; j + 4 <= jend; j += 4) {     // 4-deep MLP: 12 loads in flight
      int sA = csr_src[j],     sB = csr_src[j + 1];
      int sC = csr_src[j + 2], sD = csr_src[j + 3];
      EDGE_ACC(sA); EDGE_ACC(sB); EDGE_ACC(sC); EDGE_ACC(sD);
    }
    for (; j < jend; ++j) {
      int sA = csr_src[j];
      EDGE_ACC(sA);
    }
    float inv = 1.f / (den + 1e-16f);
    u16 o0 = f2bf(fmaxf(a0 * inv + bA.x, 0.f));
    u16 o1 = f2bf(fmaxf(a1 * inv + bA.y, 0.f));
    u16 o2 = f2bf(fmaxf(a2 * inv + bA.z, 0.f));
    u16 o3 = f2bf(fmaxf(a3 * inv + bA.w, 0.f));
    u16 o4 = f2bf(fmaxf(a4 * inv + bB.x, 0.f));
    u16 o5 = f2bf(fmaxf(a5 * inv + bB.y, 0.f));
    u16 o6 = f2bf(fmaxf(a6 * inv + bB.z, 0.f));
    u16 o7 = f2bf(fmaxf(a7 * inv + bB.w, 0.f));
    uint4 pk;
    pk.x = (u32)o0 | ((u32)o1 << 16);
    pk.y = (u32)o2 | ((u32)o3 << 16);
    pk.z = (u32)o4 | ((u32)o5 << 16);
    pk.w = (u32)o6 | ((u32)o7 << 16);
    int sw = (i & 7) << 3;
    *(uint4*)&rowsL[i * F1 + (c0 ^ sw)] = pk;
  }
  __syncthreads();
  // phase B: C[16 nodes][64 cols] = rowsL @ w2t^T; wave = (col-group g, K-half kh)
  int lane = t & 63, wid = t >> 6;       // 8 waves
  int g = wid & 3, kh = wid >> 2;
  int l16 = lane & 15, lk = (lane >> 4) * 8;
  const u16* wt = w2t + (size_t)(g * 16 + l16) * F1;
  int sw = (l16 & 7) << 3;
  f32x4 acc2 = (f32x4){0.f, 0.f, 0.f, 0.f};
  const int kbase = kh * (F1 / 2);
  for (int k0 = 0; k0 < F1 / 2; k0 += 32) {
    int kk = kbase + k0 + lk;
    bf16x8 af = *(const bf16x8*)&rowsL[l16 * F1 + (kk ^ sw)];
    bf16x8 bf = *(const bf16x8*)(wt + kk);
    acc2 = __builtin_amdgcn_mfma_f32_16x16x32_bf16(af, bf, acc2, 0, 0, 0);
  }
  int mb = (lane >> 4) * 4;
  if (kh == 1) {
    #pragma unroll
    for (int r = 0; r < 4; ++r) pb[g][mb + r][l16] = acc2[r];
  }
  __syncthreads();
  if (kh == 0) {
    int col = g * 16 + l16;
    float vals[4];
    #pragma unroll
    for (int r = 0; r < 4; ++r) vals[r] = acc2[r] + pb[g][mb + r][l16];
    if (col < C2) {
      #pragma unroll
      for (int r = 0; r < 4; ++r)
        h2[(size_t)(nb + mb + r) * C2 + col] = vals[r];
    }
    // fused att2: per-row dot with as2/ad2, reduce over 16-lane col group
    float as2v = (col < C2) ? as2c[col] : 0.f;
    float ad2v = (col < C2) ? ad2c[col] : 0.f;
    float ps[4], pd[4];
    #pragma unroll
    for (int r = 0; r < 4; ++r) { ps[r] = vals[r] * as2v; pd[r] = vals[r] * ad2v; }
    #pragma unroll
    for (int o = 1; o < 16; o <<= 1) {
      #pragma unroll
      for (int r = 0; r < 4; ++r) {
        ps[r] += __shfl_xor(ps[r], o, 64);
        pd[r] += __shfl_xor(pd[r], o, 64);
      }
    }
    if (l16 == 0 && g < 3) {   // g==3 cols are all >= C2 (zero contribution)
      #pragma unroll
      for (int r = 0; r < 4; ++r) {
        atomicAdd(&a_s2[nb + mb + r], ps[r]);
        atomicAdd(&a_d2[nb + mb + r], pd[r]);
      }
    }
  }
}

// ================= layer-2 gather + bias + log_softmax, 4 nodes/block
__global__ __launch_bounds__(256) void gath2_k(const int* __restrict__ start, const int* __restrict__ deg,
                                               const int* __restrict__ csr_src,
                                               const float* __restrict__ a_s, const float* __restrict__ a_d,
                                               const float* __restrict__ h2, const float* __restrict__ b2,
                                               void* __restrict__ outv, const int* __restrict__ flags) {
  int w = threadIdx.x >> 6, lane = threadIdx.x & 63;
  int n = blockIdx.x * 4 + w;
  int s0 = start[n], cnt = deg[n];
  float ad = a_d[n];
  float acc = 0.f, den = 0.f;
  for (int j = s0; j < s0 + cnt; ++j) {
    int s = csr_src[j];
    float v = a_s[s] + ad;
    v = v > 0.f ? v : NEG * v;
    float e = expf(v);
    den += e;
    if (lane < C2) acc += e * h2[(size_t)s * C2 + lane];
  }
  float raw = (lane < C2) ? acc / (den + 1e-16f) + b2[lane] : -1e30f;
  float m = raw;
  #pragma unroll
  for (int o = 32; o > 0; o >>= 1) m = fmaxf(m, __shfl_down(m, o, 64));
  m = __shfl(m, 0, 64);
  float e2 = (lane < C2) ? expf(raw - m) : 0.f;
  float ssum = e2;
  #pragma unroll
  for (int o = 32; o > 0; o >>= 1) ssum += __shfl_down(ssum, o, 64);
  ssum = __shfl(ssum, 0, 64);
  if (lane < C2) {
    float v = raw - m - logf(ssum);
    if (flags[1]) ((float*)outv)[(size_t)n * C2 + lane] = v;
    else          ((u16*) outv)[(size_t)n * C2 + lane] = f2bf(v);
  }
}

extern "C" void kernel_launch(void* const* d_in, const int* in_sizes, int n_in,
                              void* d_out, int out_size, void* d_ws, size_t ws_size,
                              hipStream_t stream) {
  const void* x   = d_in[0];
  const int*  ei  = (const int*)d_in[1];
  const void* W1  = d_in[2];
  const void* as1 = d_in[3];
  const void* ad1 = d_in[4];
  const void* b1  = d_in[5];
  const void* W2  = d_in[6];
  const void* as2 = d_in[7];
  const void* ad2 = d_in[8];
  const void* b2  = d_in[9];

  char* ws = (char*)d_ws;
  u16*   h1      = (u16*)  (ws);                  // 163,840,000
  float* h2      = (float*)(ws + 163840000);      //   6,720,000
  float* a_s1    = (float*)(ws + 170560000);      //   1,280,000
  float* a_d1    = (float*)(ws + 171840000);      //   1,280,000
  float* a_s2    = (float*)(ws + 173120000);      //     160,000
  float* a_d2    = (float*)(ws + 173280000);      //     160,000
  int*   deg     = (int*)  (ws + 173440000);      //     160,000
  int*   start   = (int*)  (ws + 173600000);      //     160,000
  int*   cur     = (int*)  (ws + 173760000);      //     160,000
  int*   tmp     = (int*)  (ws + 173920000);      //     160,000
  int*   csr_src = (int*)  (ws + 174080000);      //     800,000
  int*   csr_dst = (int*)  (ws + 174880000);      //     800,000
  int*   bsum    = (int*)  (ws + 175680000);      //       1,024
  u16*   w1t     = (u16*)  (ws + 175681024);      //   2,490,368
  u16*   w2t     = (u16*)  (ws + 178171392);      //     262,144
  float* as1c    = (float*)(ws + 178433536);      //       8,192
  float* ad1c    = (float*)(ws + 178441728);      //       8,192
  float* b1c     = (float*)(ws + 178449920);      //       8,192
  float* as2c    = (float*)(ws + 178458112);      //         256
  float* ad2c    = (float*)(ws + 178458368);      //         256
  float* b2c     = (float*)(ws + 178458624);      //         256
  int*   flags   = (int*)  (ws + 178458880);      //         256
  const size_t TOTAL_BASE = 178459136;
  u16*   xb      = (u16*)  (ws + TOTAL_BASE);     //  48,873,472 (path A only)
  const size_t TOTAL_A = TOTAL_BASE + (size_t)MP * KP * 2;  // 227,332,608 (< proven 233.6MB)
  if (ws_size < TOTAL_BASE) return;
  const bool pathA = (ws_size >= TOTAL_A);

  probe_k<<<1, 64, 0, stream>>>((const u32*)x, ei, flags);

  prep_k<<<8 + 64 * F1 / 256, 256, 0, stream>>>(as1, ad1, b1, as2, ad2, b2, W2,
                                                as1c, ad1c, b1c, as2c, ad2c, b2c, w2t, flags);
  w1tt_k<<<dim3(F1 / 64, (KP + 31) / 32), 256, 0, stream>>>(W1, w1t, flags);

  hipMemsetAsync(deg, 0, NN * sizeof(int), stream);
  hipMemsetAsync(a_s1, 0, (2 * NN * NH1 + 2 * NN) * sizeof(float), stream);
  const int EB = (ETOT + 255) / 256;
  deg_k  <<<EB, 256, 0, stream>>>(ei, deg, flags);
  scan1_k<<<NB, 256, 0, stream>>>(deg, tmp, bsum);
  scan3_k<<<NB, 256, 0, stream>>>(deg, tmp, bsum, start, cur);
  fill_k <<<EB, 256, 0, stream>>>(ei, cur, csr_src, csr_dst, flags);

  if (pathA) {
    xb4_k<<<MP, 192, 0, stream>>>(x, xb, flags);
    gemm1c_k<<<dim3(8, MP / 256), 512, 0, stream>>>(xb, w1t, h1, as1c, ad1c, a_s1, a_d1);
  } else {
    gemm1m_k<<<dim3(16, 313), 256, 0, stream>>>(x, w1t, h1, flags);
    att1_k<<<NN, 256, 0, stream>>>(h1, as1c, ad1c, a_s1, a_d1);
  }
  gfuse_k<<<NN / 16, 512, 0, stream>>>(start, deg, csr_src, a_s1, a_d1, h1, b1c, w2t,
                                       as2c, ad2c, h2, a_s2, a_d2);

  gath2_k<<<NN / 4, 256, 0, stream>>>(start, deg, csr_src, a_s2, a_d2, h2, b2c, d_out, flags);
}